// Round 3
// baseline (423.713 us; speedup 1.0000x reference)
//
#include <hip/hip_runtime.h>

#define HH 8
#define FOUT 128
#define DIN 64
#define NSLOPE 0.2f

typedef __attribute__((ext_vector_type(8))) short bf16x8;
typedef __attribute__((ext_vector_type(4))) float f32x4;

__device__ __forceinline__ float fast_rcp(float x) { return __builtin_amdgcn_rcpf(x); }

__device__ __forceinline__ float fast_tanh(float x) {
    float ax = fabsf(x);
    float e = __expf(-2.f * ax);
    float r = (1.f - e) * fast_rcp(1.f + e);
    return x >= 0.f ? r : -r;
}

__device__ __forceinline__ unsigned short f2bf(float f) {
    unsigned u = __builtin_bit_cast(unsigned, f);
    unsigned r = (u + 0x7fffu + ((u >> 16) & 1u)) >> 16;
    return (unsigned short)r;
}

__device__ __forceinline__ float bf2f(unsigned short u) {
    return __builtin_bit_cast(float, (unsigned)u << 16);
}

// ---------------- feature transform: h (bf16, full-line burst stores) + attention logits (LDS-staged coalesced) ----------------
__global__ __launch_bounds__(256) void k_lin(
    const float* __restrict__ x, const float* __restrict__ W, const float* __restrict__ b,
    const float* __restrict__ att0, const float* __restrict__ att1, const float* __restrict__ att2,
    unsigned short* __restrict__ hbf,
    float* __restrict__ a0, float* __restrict__ a1, float* __restrict__ a2,
    int N, int natt)
{
    __shared__ float Wl[DIN * FOUT];       // 32 KB
    __shared__ float bl[FOUT];
    __shared__ float attl[3][FOUT];
    __shared__ float aSt[3][HH][256];      // 24 KB, SoA -> conflict-free writes
    const int tid = threadIdx.x;
    for (int i = tid; i < DIN * FOUT / 4; i += 256)
        ((float4*)Wl)[i] = ((const float4*)W)[i];
    if (tid < FOUT) {
        bl[tid] = b[tid];
        attl[0][tid] = att0[tid];
        attl[1][tid] = natt > 1 ? att1[tid] : 0.f;
        attl[2][tid] = natt > 2 ? att2[tid] : 0.f;
    }
    __syncthreads();
    const int n = blockIdx.x * 256 + tid;
    const int nc = n < N ? n : N - 1;      // no early return: block syncs below

    float xr[DIN];
    const float4* xp = (const float4*)(x + (size_t)nc * DIN);
    #pragma unroll
    for (int i = 0; i < DIN / 4; i++) {
        float4 v = xp[i];
        xr[4*i] = v.x; xr[4*i+1] = v.y; xr[4*i+2] = v.z; xr[4*i+3] = v.w;
    }

    unsigned* hrow = (unsigned*)(hbf + (size_t)nc * FOUT);
    #pragma unroll
    for (int half = 0; half < 2; half++) { // one 128 B output line per half
        unsigned lrw[32];
        #pragma unroll
        for (int hh = 0; hh < 4; hh++) {
            const int h = half * 4 + hh;
            float aa0 = 0.f, aa1 = 0.f, aa2 = 0.f;
            #pragma unroll
            for (int g = 0; g < 4; g++) {
                const int fo = h * 16 + g * 4;
                float4 acc = *(const float4*)&bl[fo];
                #pragma unroll
                for (int fi = 0; fi < DIN; fi++) {
                    float4 wv = *(const float4*)&Wl[fi * FOUT + fo];  // wave-uniform -> broadcast
                    float xv = xr[fi];
                    acc.x = fmaf(xv, wv.x, acc.x);
                    acc.y = fmaf(xv, wv.y, acc.y);
                    acc.z = fmaf(xv, wv.z, acc.z);
                    acc.w = fmaf(xv, wv.w, acc.w);
                }
                lrw[hh*8 + g*2]     = ((unsigned)f2bf(acc.y) << 16) | f2bf(acc.x);
                lrw[hh*8 + g*2 + 1] = ((unsigned)f2bf(acc.w) << 16) | f2bf(acc.z);
                float4 t0 = *(const float4*)&attl[0][fo];
                aa0 += acc.x*t0.x + acc.y*t0.y + acc.z*t0.z + acc.w*t0.w;
                if (natt > 1) {
                    float4 t1 = *(const float4*)&attl[1][fo];
                    aa1 += acc.x*t1.x + acc.y*t1.y + acc.z*t1.z + acc.w*t1.w;
                    float4 t2 = *(const float4*)&attl[2][fo];
                    aa2 += acc.x*t2.x + acc.y*t2.y + acc.z*t2.z + acc.w*t2.w;
                }
            }
            aSt[0][h][tid] = aa0;
            if (natt > 1) { aSt[1][h][tid] = aa1; aSt[2][h][tid] = aa2; }
        }
        if (n < N) {
            #pragma unroll
            for (int c = 0; c < 8; c++)    // 8 x 16 B back-to-back: full line dirty at once
                ((uint4*)hrow)[half*8 + c] =
                    make_uint4(lrw[c*4], lrw[c*4+1], lrw[c*4+2], lrw[c*4+3]);
        }
    }
    __syncthreads();
    // cooperative coalesced write of the a arrays (block region is contiguous)
    const size_t gbase = (size_t)blockIdx.x * 256 * HH;
    const size_t glim = (size_t)N * HH;
    const int na = natt > 1 ? 3 : 1;
    for (int arr = 0; arr < na; arr++) {
        float* ga = arr == 0 ? a0 : (arr == 1 ? a1 : a2);
        #pragma unroll
        for (int j = 0; j < 2; j++) {
            int fi = j * 256 + tid;        // float4 index in [0,512)
            size_t gidx = gbase + (size_t)fi * 4;
            if (gidx < glim) {
                int nl = fi >> 1, hb = (fi & 1) * 4;
                float4 v;
                v.x = aSt[arr][hb+0][nl];
                v.y = aSt[arr][hb+1][nl];
                v.z = aSt[arr][hb+2][nl];
                v.w = aSt[arr][hb+3][nl];
                *(float4*)(ga + gidx) = v;
            }
        }
    }
}

// ---------------- CSR build (both edge types per dispatch) ----------------
__global__ __launch_bounds__(256) void k_deg2(
    const int* __restrict__ e0, int E0, int* __restrict__ d0,
    const int* __restrict__ e1, int E1, int* __restrict__ d1)
{
    int t = blockIdx.x * 256 + threadIdx.x;
    if (t < E0) atomicAdd(&d0[e0[E0 + t]], 1);
    if (t < E1) atomicAdd(&d1[e1[E1 + t]], 1);
}

__global__ __launch_bounds__(256) void k_scan_block2(
    const int* __restrict__ in0, int* __restrict__ out0, int* __restrict__ bs0,
    const int* __restrict__ in1, int* __restrict__ out1, int* __restrict__ bs1, int n)
{
    const int* in = blockIdx.y ? in1 : in0;
    int* out = blockIdx.y ? out1 : out0;
    int* bsum = blockIdx.y ? bs1 : bs0;
    __shared__ int s[256];
    const int tid = threadIdx.x;
    const int i = blockIdx.x * 256 + tid;
    int v = i < n ? in[i] : 0;
    s[tid] = v; __syncthreads();
    for (int off = 1; off < 256; off <<= 1) {
        int t = tid >= off ? s[tid - off] : 0;
        __syncthreads();
        s[tid] += t;
        __syncthreads();
    }
    if (i < n) out[i] = s[tid] - v;
    if (tid == 255) bsum[blockIdx.x] = s[255];
}

__global__ __launch_bounds__(512) void k_scan_partial2(int* __restrict__ b0, int* __restrict__ b1, int nb) {
    int* bs = blockIdx.x ? b1 : b0;
    __shared__ int s[512];
    const int tid = threadIdx.x;
    int v = tid < nb ? bs[tid] : 0;
    s[tid] = v; __syncthreads();
    for (int off = 1; off < 512; off <<= 1) {
        int t = tid >= off ? s[tid - off] : 0;
        __syncthreads();
        s[tid] += t;
        __syncthreads();
    }
    if (tid < nb) bs[tid] = s[tid] - v;
}

__global__ __launch_bounds__(256) void k_scan_add2(
    int* __restrict__ o0, const int* __restrict__ b0,
    int* __restrict__ o1, const int* __restrict__ b1, int n)
{
    int* out = blockIdx.y ? o1 : o0;
    const int* bsum = blockIdx.y ? b1 : b0;
    int i = blockIdx.x * 256 + threadIdx.x;
    if (i < n) out[i] += bsum[blockIdx.x];
}

__global__ __launch_bounds__(256) void k_scatter2(
    const int* __restrict__ e0, int E0, const int* __restrict__ rp0, int* __restrict__ c0, int* __restrict__ sl0,
    const int* __restrict__ e1, int E1, const int* __restrict__ rp1, int* __restrict__ c1, int* __restrict__ sl1)
{
    int t = blockIdx.x * 256 + threadIdx.x;
    if (t < E0) {
        int src = e0[t], dst = e0[E0 + t];
        sl0[rp0[dst] + atomicAdd(&c0[dst], 1)] = src;
    }
    if (t < E1) {
        int src = e1[t], dst = e1[E1 + t];
        sl1[rp1[dst] + atomicAdd(&c1[dst], 1)] = src;
    }
}

// ---------------- aggregation: 32 lanes per dst, bf16 gathers, fused norm+relu ----------------
__global__ __launch_bounds__(256) void k_agg2(
    const int* __restrict__ sl0, const int* __restrict__ rp0, const int* __restrict__ dg0,
    const unsigned short* __restrict__ xb0, const float* __restrict__ as0, const float* __restrict__ ad0,
    float* __restrict__ oo0,
    const int* __restrict__ sl1, const int* __restrict__ rp1, const int* __restrict__ dg1,
    const unsigned short* __restrict__ xb1, const float* __restrict__ as1, const float* __restrict__ ad1,
    float* __restrict__ oo1,
    int N)
{
    const bool m = blockIdx.y;
    const int* __restrict__ sl = m ? sl1 : sl0;
    const int* __restrict__ rp = m ? rp1 : rp0;
    const int* __restrict__ dg = m ? dg1 : dg0;
    const unsigned short* __restrict__ xb = m ? xb1 : xb0;
    const float* __restrict__ as_ = m ? as1 : as0;
    const float* __restrict__ ad_ = m ? ad1 : ad0;
    float* __restrict__ oo = m ? oo1 : oo0;

    const int t = blockIdx.x * 256 + threadIdx.x;
    const int dst = t >> 5;
    if (dst >= N) return;
    const int lane = t & 31;
    const int h = lane >> 2;
    const int d = dg[dst];
    const int base = rp[dst];
    const float adv = ad_[(size_t)dst * HH + h];
    float acc0 = 0.f, acc1 = 0.f, acc2 = 0.f, acc3 = 0.f;
    float wsum = 0.f;
    int src_next = d > 0 ? sl[base] : 0;
    for (int k = 0; k < d; k++) {
        int src = src_next;
        if (k + 1 < d) src_next = sl[base + k + 1];
        float a = as_[(size_t)src * HH + h] + adv;
        a = a > 0.f ? a : NSLOPE * a;
        float wv = __expf(a);
        uint2 xv = *(const uint2*)(xb + (size_t)src * FOUT + lane * 4);  // 4 bf16
        acc0 = fmaf(wv, bf2f((unsigned short)(xv.x & 0xffff)), acc0);
        acc1 = fmaf(wv, bf2f((unsigned short)(xv.x >> 16)), acc1);
        acc2 = fmaf(wv, bf2f((unsigned short)(xv.y & 0xffff)), acc2);
        acc3 = fmaf(wv, bf2f((unsigned short)(xv.y >> 16)), acc3);
        wsum += wv;
    }
    float inv = fast_rcp(wsum + 1e-16f);
    float4 o;
    o.x = fmaxf(acc0 * inv, 0.f);
    o.y = fmaxf(acc1 * inv, 0.f);
    o.z = fmaxf(acc2 * inv, 0.f);
    o.w = fmaxf(acc3 * inv, 0.f);
    *(float4*)(oo + (size_t)dst * FOUT + lane * 4) = o;
}

// ---------------- semantic score: bf16 MFMA GEMM + tanh·q reduce ----------------
__global__ __launch_bounds__(256) void k_sem(
    const float* __restrict__ o1, const float* __restrict__ o2,
    const float* __restrict__ kw, const float* __restrict__ kb,
    const float* __restrict__ q, float* __restrict__ score, int N)
{
    __shared__ unsigned short kwl[FOUT * FOUT];  // kw^T bf16, chunk-XOR swizzled
    __shared__ float red[256];
    const int tid = threadIdx.x;
    const int m = blockIdx.y;
    const float* o = m ? o2 : o1;

    for (int idx = tid; idx < FOUT * FOUT; idx += 256) {
        int fi = idx >> 7, fo = idx & 127;
        int c = (fi >> 3) ^ (fo & 15);
        kwl[fo * 128 + c * 8 + (fi & 7)] = f2bf(kw[idx]);
    }
    __syncthreads();

    const int lane = tid & 63;
    const int w = tid >> 6;
    const int n0 = blockIdx.x * 256 + w * 64;
    const int r16 = lane & 15;
    const int g = lane >> 4;

    float qv[8], kbv[8];
    #pragma unroll
    for (int j = 0; j < 8; j++) { qv[j] = q[j * 16 + r16]; kbv[j] = kb[j * 16 + r16]; }

    bf16x8 afrag[4][4];
    #pragma unroll
    for (int i = 0; i < 4; i++) {
        int node = n0 + i * 16 + r16;
        if (node > N - 1) node = N - 1;
        const float* rowp = o + (size_t)node * FOUT + g * 8;
        #pragma unroll
        for (int kk = 0; kk < 4; kk++) {
            float4 v0 = *(const float4*)(rowp + kk * 32);
            float4 v1 = *(const float4*)(rowp + kk * 32 + 4);
            bf16x8 f;
            f[0] = (short)f2bf(v0.x); f[1] = (short)f2bf(v0.y);
            f[2] = (short)f2bf(v0.z); f[3] = (short)f2bf(v0.w);
            f[4] = (short)f2bf(v1.x); f[5] = (short)f2bf(v1.y);
            f[6] = (short)f2bf(v1.z); f[7] = (short)f2bf(v1.w);
            afrag[i][kk] = f;
        }
    }

    float part = 0.f;
    #pragma unroll
    for (int j = 0; j < 8; j++) {
        const int fo = j * 16 + r16;
        f32x4 acc0 = {0.f,0.f,0.f,0.f}, acc1 = {0.f,0.f,0.f,0.f};
        f32x4 acc2 = {0.f,0.f,0.f,0.f}, acc3 = {0.f,0.f,0.f,0.f};
        #pragma unroll
        for (int kk = 0; kk < 4; kk++) {
            int c = (kk * 4 + g) ^ (fo & 15);
            bf16x8 bfr = *(bf16x8*)&kwl[fo * 128 + c * 8];
            acc0 = __builtin_amdgcn_mfma_f32_16x16x32_bf16(afrag[0][kk], bfr, acc0, 0, 0, 0);
            acc1 = __builtin_amdgcn_mfma_f32_16x16x32_bf16(afrag[1][kk], bfr, acc1, 0, 0, 0);
            acc2 = __builtin_amdgcn_mfma_f32_16x16x32_bf16(afrag[2][kk], bfr, acc2, 0, 0, 0);
            acc3 = __builtin_amdgcn_mfma_f32_16x16x32_bf16(afrag[3][kk], bfr, acc3, 0, 0, 0);
        }
        #pragma unroll
        for (int i = 0; i < 4; i++) {
            f32x4 a = i == 0 ? acc0 : (i == 1 ? acc1 : (i == 2 ? acc2 : acc3));
            #pragma unroll
            for (int r = 0; r < 4; r++) {
                int node = n0 + i * 16 + g * 4 + r;
                if (node < N) part += fast_tanh(a[r] + kbv[j]) * qv[j];
            }
        }
    }
    red[tid] = part;
    __syncthreads();
    for (int s2 = 128; s2 > 0; s2 >>= 1) {
        if (tid < s2) red[tid] += red[tid + s2];
        __syncthreads();
    }
    if (tid == 0) atomicAdd(score + m, red[0]);
}

__global__ void k_attn(const float* __restrict__ score, float* __restrict__ attn, float invN) {
    if (threadIdx.x == 0) {
        float s0 = score[0] * invN, s1 = score[1] * invN;
        float mm = fmaxf(s0, s1);
        float e0 = __expf(s0 - mm), e1 = __expf(s1 - mm);
        float inv = 1.f / (e0 + e1);
        attn[0] = e0 * inv;
        attn[1] = e1 * inv;
    }
}

__global__ __launch_bounds__(256) void k_final(
    const float* __restrict__ o1, const float* __restrict__ o2,
    const float* __restrict__ attn,
    const float* __restrict__ lw, const float* __restrict__ lb,
    float* __restrict__ out, int N)
{
    __shared__ float lwl[FOUT * 2];
    const int tid = threadIdx.x;
    if (tid < FOUT * 2) lwl[tid] = lw[tid];
    __syncthreads();
    const int n = blockIdx.x * 256 + tid;
    if (n >= N) return;
    const float a0 = attn[0], a1 = attn[1];
    float acc0 = lb[0], acc1 = lb[1];
    const float4* p1 = (const float4*)(o1 + (size_t)n * FOUT);
    const float4* p2 = (const float4*)(o2 + (size_t)n * FOUT);
    #pragma unroll
    for (int i = 0; i < FOUT / 4; i++) {
        float4 v1 = p1[i];
        float4 v2 = p2[i];
        float f0 = a0 * v1.x + a1 * v2.x;
        float f1 = a0 * v1.y + a1 * v2.y;
        float f2 = a0 * v1.z + a1 * v2.z;
        float f3 = a0 * v1.w + a1 * v2.w;
        int f = i * 4;
        acc0 += f0 * lwl[f*2]   + f1 * lwl[(f+1)*2]   + f2 * lwl[(f+2)*2]   + f3 * lwl[(f+3)*2];
        acc1 += f0 * lwl[f*2+1] + f1 * lwl[(f+1)*2+1] + f2 * lwl[(f+2)*2+1] + f3 * lwl[(f+3)*2+1];
    }
    *(float2*)(out + (size_t)n * 2) = make_float2(acc0, acc1);
}

extern "C" void kernel_launch(void* const* d_in, const int* in_sizes, int n_in,
                              void* d_out, int out_size, void* d_ws, size_t ws_size,
                              hipStream_t stream)
{
    const float* x_subj = (const float*)d_in[0];
    const float* x_chan = (const float*)d_in[1];
    const int*   e_cs   = (const int*)d_in[2];
    const int*   e_ss   = (const int*)d_in[3];
    const float* W_s    = (const float*)d_in[4];
    const float* b_s    = (const float*)d_in[5];
    const float* W_c    = (const float*)d_in[6];
    const float* b_c    = (const float*)d_in[7];
    const float* att_src_cs = (const float*)d_in[8];
    const float* att_dst_cs = (const float*)d_in[9];
    const float* att_src_ss = (const float*)d_in[10];
    const float* att_dst_ss = (const float*)d_in[11];
    const float* k_w  = (const float*)d_in[12];
    const float* k_b  = (const float*)d_in[13];
    const float* q    = (const float*)d_in[14];
    const float* lw   = (const float*)d_in[15];
    const float* lb   = (const float*)d_in[16];

    const int Ns  = in_sizes[0] / DIN;
    const int Nc  = in_sizes[1] / DIN;
    const int Ecs = in_sizes[2] / 2;
    const int Ess = in_sizes[3] / 2;

    // ---- workspace layout (all chunks 16B-aligned) ----
    char* p = (char*)d_ws;
    unsigned short* hbf_s = (unsigned short*)p; p += (size_t)Ns * FOUT * 2;
    unsigned short* hbf_c = (unsigned short*)p; p += (size_t)Nc * FOUT * 2;
    float* a_src_cs_ = (float*)p; p += (size_t)Nc * HH * 4;
    float* a_dst_cs_ = (float*)p; p += (size_t)Ns * HH * 4;
    float* a_src_ss_ = (float*)p; p += (size_t)Ns * HH * 4;
    float* a_dst_ss_ = (float*)p; p += (size_t)Ns * HH * 4;
    float* o1        = (float*)p; p += (size_t)Ns * FOUT * 4;
    float* o2        = (float*)p; p += (size_t)Ns * FOUT * 4;
    int* srclist_cs  = (int*)p;   p += (size_t)Ecs * 4;
    int* srclist_ss  = (int*)p;   p += (size_t)Ess * 4;
    int* rowptr_cs   = (int*)p;   p += (size_t)Ns * 4;
    int* rowptr_ss   = (int*)p;   p += (size_t)Ns * 4;
    int* bsum0       = (int*)p;   p += 2048;
    int* bsum1       = (int*)p;   p += 2048;
    // zeroed region:
    char* zstart = p;
    int* deg_cs = (int*)p; p += (size_t)Ns * 4;
    int* deg_ss = (int*)p; p += (size_t)Ns * 4;
    int* cnt_cs = (int*)p; p += (size_t)Ns * 4;
    int* cnt_ss = (int*)p; p += (size_t)Ns * 4;
    float* score = (float*)p; p += 16;   // [s0, s1, attn0, attn1]
    hipMemsetAsync(zstart, 0, (size_t)Ns * 4 * 4 + 16, stream);

    const int nbN = (Ns + 255) / 256;
    const int nbE = ((Ecs > Ess ? Ecs : Ess) + 255) / 256;

    k_lin<<<dim3(nbN), dim3(256), 0, stream>>>(
        x_subj, W_s, b_s, att_dst_cs, att_src_ss, att_dst_ss,
        hbf_s, a_dst_cs_, a_src_ss_, a_dst_ss_, Ns, 3);
    k_lin<<<dim3((Nc + 255) / 256), dim3(256), 0, stream>>>(
        x_chan, W_c, b_c, att_src_cs, att_src_cs, att_src_cs,
        hbf_c, a_src_cs_, a_src_cs_, a_src_cs_, Nc, 1);

    // CSR build, both edge types per dispatch
    k_deg2<<<dim3(nbE), dim3(256), 0, stream>>>(e_cs, Ecs, deg_cs, e_ss, Ess, deg_ss);
    k_scan_block2<<<dim3(nbN, 2), dim3(256), 0, stream>>>(
        deg_cs, rowptr_cs, bsum0, deg_ss, rowptr_ss, bsum1, Ns);
    k_scan_partial2<<<dim3(2), dim3(512), 0, stream>>>(bsum0, bsum1, nbN);
    k_scan_add2<<<dim3(nbN, 2), dim3(256), 0, stream>>>(rowptr_cs, bsum0, rowptr_ss, bsum1, Ns);
    k_scatter2<<<dim3(nbE), dim3(256), 0, stream>>>(
        e_cs, Ecs, rowptr_cs, cnt_cs, srclist_cs,
        e_ss, Ess, rowptr_ss, cnt_ss, srclist_ss);

    // aggregation (fused softmax-normalize + relu), both metapaths
    k_agg2<<<dim3(((size_t)Ns * 32 + 255) / 256, 2), dim3(256), 0, stream>>>(
        srclist_cs, rowptr_cs, deg_cs, hbf_c, a_src_cs_, a_dst_cs_, o1,
        srclist_ss, rowptr_ss, deg_ss, hbf_s, a_src_ss_, a_dst_ss_, o2, Ns);

    // semantic attention + fuse + output
    k_sem<<<dim3(nbN, 2), dim3(256), 0, stream>>>(o1, o2, k_w, k_b, q, score, Ns);
    k_attn<<<dim3(1), dim3(64), 0, stream>>>(score, score + 2, 1.f / (float)Ns);
    k_final<<<dim3(nbN), dim3(256), 0, stream>>>(o1, o2, score + 2, lw, lb, (float*)d_out, Ns);
}

// Round 4
// 301.149 us; speedup vs baseline: 1.4070x; 1.4070x over previous
//
#include <hip/hip_runtime.h>

#define HH 8
#define FOUT 128
#define DIN 64
#define NCOL 160          // 128 h cols + 24 logit cols + 8 pad (10 MFMA j-tiles)
#define NSLOPE 0.2f

typedef __attribute__((ext_vector_type(8))) short bf16x8;
typedef __attribute__((ext_vector_type(4))) float f32x4;

__device__ __forceinline__ float fast_rcp(float x) { return __builtin_amdgcn_rcpf(x); }

__device__ __forceinline__ float fast_tanh(float x) {
    float ax = fabsf(x);
    float e = __expf(-2.f * ax);
    float r = (1.f - e) * fast_rcp(1.f + e);
    return x >= 0.f ? r : -r;
}

__device__ __forceinline__ unsigned short f2bf(float f) {
    unsigned u = __builtin_bit_cast(unsigned, f);
    unsigned r = (u + 0x7fffu + ((u >> 16) & 1u)) >> 16;
    return (unsigned short)r;
}

__device__ __forceinline__ float bf2f(unsigned short u) {
    return __builtin_bit_cast(float, (unsigned)u << 16);
}

// ---------------- feature transform via MFMA, logits as augmented GEMM columns ----------------
// Computes h = x@W + b (stored bf16) and a_k[n,h] = h[n,head]·att_k via pre-contracted
// columns w~[fi, 24] = sum_{fo in head} W[fi,fo]*att[fo]; abias = b·att.
__global__ __launch_bounds__(256) void k_linm(
    const float* __restrict__ x0, const float* __restrict__ W0, const float* __restrict__ b0,
    const float* __restrict__ A00, const float* __restrict__ A01, const float* __restrict__ A02,
    unsigned short* __restrict__ h0,
    float* __restrict__ a00, float* __restrict__ a01, float* __restrict__ a02, int N0, int natt0,
    const float* __restrict__ x1, const float* __restrict__ W1, const float* __restrict__ b1,
    const float* __restrict__ A10, const float* __restrict__ A11, const float* __restrict__ A12,
    unsigned short* __restrict__ h1,
    float* __restrict__ a10, float* __restrict__ a11, float* __restrict__ a12, int N1, int natt1)
{
    const int y = blockIdx.y;
    const float* __restrict__ x  = y ? x1 : x0;
    const float* __restrict__ W  = y ? W1 : W0;
    const float* __restrict__ b  = y ? b1 : b0;
    const float* __restrict__ at0 = y ? A10 : A00;
    const float* __restrict__ at1 = y ? A11 : A01;
    const float* __restrict__ at2 = y ? A12 : A02;
    unsigned short* __restrict__ hb = y ? h1 : h0;
    float* __restrict__ a0 = y ? a10 : a00;
    float* __restrict__ a1 = y ? a11 : a01;
    float* __restrict__ a2 = y ? a12 : a02;
    const int N = y ? N1 : N0;
    const int natt = y ? natt1 : natt0;

    __shared__ unsigned short wtl[NCOL * DIN];  // W^T bf16, chunk-XOR swizzled (20 KB)
    __shared__ float attl[3][FOUT];
    __shared__ float bl[FOUT];
    __shared__ float abias[32];
    const int tid = threadIdx.x;

    if (tid < FOUT) {
        bl[tid] = b[tid];
        attl[0][tid] = at0[tid];
        attl[1][tid] = at1[tid];
        attl[2][tid] = at2[tid];
    }
    __syncthreads();

    // W columns 0..127: element (fi,fo) -> row fo, chunk (fi>>3)^(fo&7), slot fi&7
    for (int idx = tid; idx < DIN * FOUT; idx += 256) {
        int fi = idx >> 7, fo = idx & 127;
        wtl[fo * DIN + (((fi >> 3) ^ (fo & 7)) << 3) + (fi & 7)] = f2bf(W[idx]);
    }
    // augmented columns 128..151 (w~), 152..159 pad
    for (int idx = tid; idx < 2048; idx += 256) {
        int fi = idx >> 5, cs = idx & 31;
        float acc = 0.f;
        if (cs < 24) {
            int a = cs >> 3, hd = cs & 7;
            #pragma unroll
            for (int d = 0; d < 16; d++)
                acc += W[fi * FOUT + hd * 16 + d] * attl[a][hd * 16 + d];
        }
        int fo = 128 + cs;
        wtl[fo * DIN + (((fi >> 3) ^ (fo & 7)) << 3) + (fi & 7)] =
            cs < 24 ? f2bf(acc) : (unsigned short)0;
    }
    if (tid < 32) {
        float acc = 0.f;
        if (tid < 24) {
            int a = tid >> 3, hd = tid & 7;
            #pragma unroll
            for (int d = 0; d < 16; d++) acc += b[hd * 16 + d] * attl[a][hd * 16 + d];
        }
        abias[tid] = acc;
    }
    __syncthreads();

    const int w = tid >> 6, lane = tid & 63;
    const int rt = blockIdx.x * 4 + w;           // 16-node row tile per wave
    if (rt * 16 >= N) return;
    const int r16 = lane & 15, g = lane >> 4;

    int node = rt * 16 + r16;
    if (node >= N) node = N - 1;
    const float* xr = x + (size_t)node * DIN;
    bf16x8 af[2];
    #pragma unroll
    for (int kk = 0; kk < 2; kk++) {            // A: row=lane&15, k=kk*32+g*8+b
        float4 v0 = *(const float4*)(xr + kk * 32 + g * 8);
        float4 v1 = *(const float4*)(xr + kk * 32 + g * 8 + 4);
        bf16x8 f;
        f[0] = (short)f2bf(v0.x); f[1] = (short)f2bf(v0.y);
        f[2] = (short)f2bf(v0.z); f[3] = (short)f2bf(v0.w);
        f[4] = (short)f2bf(v1.x); f[5] = (short)f2bf(v1.y);
        f[6] = (short)f2bf(v1.z); f[7] = (short)f2bf(v1.w);
        af[kk] = f;
    }

    #pragma unroll
    for (int j = 0; j < 10; j++) {
        const int fo = j * 16 + r16;
        f32x4 acc = {0.f, 0.f, 0.f, 0.f};
        #pragma unroll
        for (int kk = 0; kk < 2; kk++) {
            int c = (kk * 4 + g) ^ (fo & 7);
            bf16x8 bfr = *(bf16x8*)&wtl[fo * DIN + c * 8];
            acc = __builtin_amdgcn_mfma_f32_16x16x32_bf16(af[kk], bfr, acc, 0, 0, 0);
        }
        // D: row = g*4+r (node within tile), col = lane&15
        if (j < 8) {
            float bv = bl[fo];
            #pragma unroll
            for (int r = 0; r < 4; r++) {
                int nr = rt * 16 + g * 4 + r;
                if (nr < N) hb[(size_t)nr * FOUT + fo] = f2bf(acc[r] + bv);
            }
        } else {
            int cs = (j - 8) * 16 + r16;         // 0..31
            if (cs < 24) {
                int a = cs >> 3;
                if (a < natt) {
                    float* __restrict__ ga = a == 0 ? a0 : (a == 1 ? a1 : a2);
                    int hd = cs & 7;
                    float ab = abias[cs];
                    #pragma unroll
                    for (int r = 0; r < 4; r++) {
                        int nr = rt * 16 + g * 4 + r;
                        if (nr < N) ga[(size_t)nr * HH + hd] = acc[r] + ab;
                    }
                }
            }
        }
    }
}

// ---------------- CSR build (both edge types per dispatch) ----------------
__global__ __launch_bounds__(256) void k_deg2(
    const int* __restrict__ e0, int E0, int* __restrict__ d0,
    const int* __restrict__ e1, int E1, int* __restrict__ d1)
{
    int t = blockIdx.x * 256 + threadIdx.x;
    if (t < E0) atomicAdd(&d0[e0[E0 + t]], 1);
    if (t < E1) atomicAdd(&d1[e1[E1 + t]], 1);
}

__global__ __launch_bounds__(256) void k_scan_block2(
    const int* __restrict__ in0, int* __restrict__ out0, int* __restrict__ bs0,
    const int* __restrict__ in1, int* __restrict__ out1, int* __restrict__ bs1, int n)
{
    const int* in = blockIdx.y ? in1 : in0;
    int* out = blockIdx.y ? out1 : out0;
    int* bsum = blockIdx.y ? bs1 : bs0;
    __shared__ int s[256];
    const int tid = threadIdx.x;
    const int i = blockIdx.x * 256 + tid;
    int v = i < n ? in[i] : 0;
    s[tid] = v; __syncthreads();
    for (int off = 1; off < 256; off <<= 1) {
        int t = tid >= off ? s[tid - off] : 0;
        __syncthreads();
        s[tid] += t;
        __syncthreads();
    }
    if (i < n) out[i] = s[tid] - v;
    if (tid == 255) bsum[blockIdx.x] = s[255];
}

__global__ __launch_bounds__(512) void k_scan_partial2(int* __restrict__ b0, int* __restrict__ b1, int nb) {
    int* bs = blockIdx.x ? b1 : b0;
    __shared__ int s[512];
    const int tid = threadIdx.x;
    int v = tid < nb ? bs[tid] : 0;
    s[tid] = v; __syncthreads();
    for (int off = 1; off < 512; off <<= 1) {
        int t = tid >= off ? s[tid - off] : 0;
        __syncthreads();
        s[tid] += t;
        __syncthreads();
    }
    if (tid < nb) bs[tid] = s[tid] - v;
}

__global__ __launch_bounds__(256) void k_scan_add2(
    int* __restrict__ o0, const int* __restrict__ b0,
    int* __restrict__ o1, const int* __restrict__ b1, int n)
{
    int* out = blockIdx.y ? o1 : o0;
    const int* bsum = blockIdx.y ? b1 : b0;
    int i = blockIdx.x * 256 + threadIdx.x;
    if (i < n) out[i] += bsum[blockIdx.x];
}

__global__ __launch_bounds__(256) void k_scatter2(
    const int* __restrict__ e0, int E0, const int* __restrict__ rp0, int* __restrict__ c0, int* __restrict__ sl0,
    const int* __restrict__ e1, int E1, const int* __restrict__ rp1, int* __restrict__ c1, int* __restrict__ sl1)
{
    int t = blockIdx.x * 256 + threadIdx.x;
    if (t < E0) {
        int src = e0[t], dst = e0[E0 + t];
        sl0[rp0[dst] + atomicAdd(&c0[dst], 1)] = src;
    }
    if (t < E1) {
        int src = e1[t], dst = e1[E1 + t];
        sl1[rp1[dst] + atomicAdd(&c1[dst], 1)] = src;
    }
}

// ---------------- aggregation: 32 lanes per dst, bf16 gathers, fused norm+relu ----------------
__global__ __launch_bounds__(256) void k_agg2(
    const int* __restrict__ sl0, const int* __restrict__ rp0, const int* __restrict__ dg0,
    const unsigned short* __restrict__ xb0, const float* __restrict__ as0, const float* __restrict__ ad0,
    float* __restrict__ oo0,
    const int* __restrict__ sl1, const int* __restrict__ rp1, const int* __restrict__ dg1,
    const unsigned short* __restrict__ xb1, const float* __restrict__ as1, const float* __restrict__ ad1,
    float* __restrict__ oo1,
    int N)
{
    const bool m = blockIdx.y;
    const int* __restrict__ sl = m ? sl1 : sl0;
    const int* __restrict__ rp = m ? rp1 : rp0;
    const int* __restrict__ dg = m ? dg1 : dg0;
    const unsigned short* __restrict__ xb = m ? xb1 : xb0;
    const float* __restrict__ as_ = m ? as1 : as0;
    const float* __restrict__ ad_ = m ? ad1 : ad0;
    float* __restrict__ oo = m ? oo1 : oo0;

    const int t = blockIdx.x * 256 + threadIdx.x;
    const int dst = t >> 5;
    if (dst >= N) return;
    const int lane = t & 31;
    const int h = lane >> 2;
    const int d = dg[dst];
    const int base = rp[dst];
    const float adv = ad_[(size_t)dst * HH + h];
    float acc0 = 0.f, acc1 = 0.f, acc2 = 0.f, acc3 = 0.f;
    float wsum = 0.f;
    int src_next = d > 0 ? sl[base] : 0;
    for (int k = 0; k < d; k++) {
        int src = src_next;
        if (k + 1 < d) src_next = sl[base + k + 1];
        float a = as_[(size_t)src * HH + h] + adv;
        a = a > 0.f ? a : NSLOPE * a;
        float wv = __expf(a);
        uint2 xv = *(const uint2*)(xb + (size_t)src * FOUT + lane * 4);  // 4 bf16
        acc0 = fmaf(wv, bf2f((unsigned short)(xv.x & 0xffff)), acc0);
        acc1 = fmaf(wv, bf2f((unsigned short)(xv.x >> 16)), acc1);
        acc2 = fmaf(wv, bf2f((unsigned short)(xv.y & 0xffff)), acc2);
        acc3 = fmaf(wv, bf2f((unsigned short)(xv.y >> 16)), acc3);
        wsum += wv;
    }
    float inv = fast_rcp(wsum + 1e-16f);
    float4 o;
    o.x = fmaxf(acc0 * inv, 0.f);
    o.y = fmaxf(acc1 * inv, 0.f);
    o.z = fmaxf(acc2 * inv, 0.f);
    o.w = fmaxf(acc3 * inv, 0.f);
    *(float4*)&oo[(size_t)dst * FOUT + lane * 4] = o;
}

// ---------------- semantic score: bf16 MFMA GEMM + tanh·q reduce ----------------
__global__ __launch_bounds__(256) void k_sem(
    const float* __restrict__ o1, const float* __restrict__ o2,
    const float* __restrict__ kw, const float* __restrict__ kb,
    const float* __restrict__ q, float* __restrict__ score, int N)
{
    __shared__ unsigned short kwl[FOUT * FOUT];  // kw^T bf16, chunk-XOR swizzled
    __shared__ float red[256];
    const int tid = threadIdx.x;
    const int m = blockIdx.y;
    const float* o = m ? o2 : o1;

    for (int idx = tid; idx < FOUT * FOUT; idx += 256) {
        int fi = idx >> 7, fo = idx & 127;
        int c = (fi >> 3) ^ (fo & 15);
        kwl[fo * 128 + c * 8 + (fi & 7)] = f2bf(kw[idx]);
    }
    __syncthreads();

    const int lane = tid & 63;
    const int w = tid >> 6;
    const int n0 = blockIdx.x * 256 + w * 64;
    const int r16 = lane & 15;
    const int g = lane >> 4;

    float qv[8], kbv[8];
    #pragma unroll
    for (int j = 0; j < 8; j++) { qv[j] = q[j * 16 + r16]; kbv[j] = kb[j * 16 + r16]; }

    bf16x8 afrag[4][4];
    #pragma unroll
    for (int i = 0; i < 4; i++) {
        int node = n0 + i * 16 + r16;
        if (node > N - 1) node = N - 1;
        const float* rowp = o + (size_t)node * FOUT + g * 8;
        #pragma unroll
        for (int kk = 0; kk < 4; kk++) {
            float4 v0 = *(const float4*)(rowp + kk * 32);
            float4 v1 = *(const float4*)(rowp + kk * 32 + 4);
            bf16x8 f;
            f[0] = (short)f2bf(v0.x); f[1] = (short)f2bf(v0.y);
            f[2] = (short)f2bf(v0.z); f[3] = (short)f2bf(v0.w);
            f[4] = (short)f2bf(v1.x); f[5] = (short)f2bf(v1.y);
            f[6] = (short)f2bf(v1.z); f[7] = (short)f2bf(v1.w);
            afrag[i][kk] = f;
        }
    }

    float part = 0.f;
    #pragma unroll
    for (int j = 0; j < 8; j++) {
        const int fo = j * 16 + r16;
        f32x4 acc0 = {0.f,0.f,0.f,0.f}, acc1 = {0.f,0.f,0.f,0.f};
        f32x4 acc2 = {0.f,0.f,0.f,0.f}, acc3 = {0.f,0.f,0.f,0.f};
        #pragma unroll
        for (int kk = 0; kk < 4; kk++) {
            int c = (kk * 4 + g) ^ (fo & 15);
            bf16x8 bfr = *(bf16x8*)&kwl[fo * 128 + c * 8];
            acc0 = __builtin_amdgcn_mfma_f32_16x16x32_bf16(afrag[0][kk], bfr, acc0, 0, 0, 0);
            acc1 = __builtin_amdgcn_mfma_f32_16x16x32_bf16(afrag[1][kk], bfr, acc1, 0, 0, 0);
            acc2 = __builtin_amdgcn_mfma_f32_16x16x32_bf16(afrag[2][kk], bfr, acc2, 0, 0, 0);
            acc3 = __builtin_amdgcn_mfma_f32_16x16x32_bf16(afrag[3][kk], bfr, acc3, 0, 0, 0);
        }
        #pragma unroll
        for (int i = 0; i < 4; i++) {
            f32x4 a = i == 0 ? acc0 : (i == 1 ? acc1 : (i == 2 ? acc2 : acc3));
            #pragma unroll
            for (int r = 0; r < 4; r++) {
                int node = n0 + i * 16 + g * 4 + r;
                if (node < N) part += fast_tanh(a[r] + kbv[j]) * qv[j];
            }
        }
    }
    red[tid] = part;
    __syncthreads();
    for (int s2 = 128; s2 > 0; s2 >>= 1) {
        if (tid < s2) red[tid] += red[tid + s2];
        __syncthreads();
    }
    if (tid == 0) atomicAdd(score + m, red[0]);
}

__global__ void k_attn(const float* __restrict__ score, float* __restrict__ attn, float invN) {
    if (threadIdx.x == 0) {
        float s0 = score[0] * invN, s1 = score[1] * invN;
        float mm = fmaxf(s0, s1);
        float e0 = __expf(s0 - mm), e1 = __expf(s1 - mm);
        float inv = 1.f / (e0 + e1);
        attn[0] = e0 * inv;
        attn[1] = e1 * inv;
    }
}

__global__ __launch_bounds__(256) void k_final(
    const float* __restrict__ o1, const float* __restrict__ o2,
    const float* __restrict__ attn,
    const float* __restrict__ lw, const float* __restrict__ lb,
    float* __restrict__ out, int N)
{
    __shared__ float lwl[FOUT * 2];
    const int tid = threadIdx.x;
    if (tid < FOUT * 2) lwl[tid] = lw[tid];
    __syncthreads();
    const int n = blockIdx.x * 256 + tid;
    if (n >= N) return;
    const float a0 = attn[0], a1 = attn[1];
    float acc0 = lb[0], acc1 = lb[1];
    const float4* p1 = (const float4*)(o1 + (size_t)n * FOUT);
    const float4* p2 = (const float4*)(o2 + (size_t)n * FOUT);
    #pragma unroll
    for (int i = 0; i < FOUT / 4; i++) {
        float4 v1 = p1[i];
        float4 v2 = p2[i];
        float f0 = a0 * v1.x + a1 * v2.x;
        float f1 = a0 * v1.y + a1 * v2.y;
        float f2 = a0 * v1.z + a1 * v2.z;
        float f3 = a0 * v1.w + a1 * v2.w;
        int f = i * 4;
        acc0 += f0 * lwl[f*2]   + f1 * lwl[(f+1)*2]   + f2 * lwl[(f+2)*2]   + f3 * lwl[(f+3)*2];
        acc1 += f0 * lwl[f*2+1] + f1 * lwl[(f+1)*2+1] + f2 * lwl[(f+2)*2+1] + f3 * lwl[(f+3)*2+1];
    }
    *(float2*)(out + (size_t)n * 2) = make_float2(acc0, acc1);
}

extern "C" void kernel_launch(void* const* d_in, const int* in_sizes, int n_in,
                              void* d_out, int out_size, void* d_ws, size_t ws_size,
                              hipStream_t stream)
{
    const float* x_subj = (const float*)d_in[0];
    const float* x_chan = (const float*)d_in[1];
    const int*   e_cs   = (const int*)d_in[2];
    const int*   e_ss   = (const int*)d_in[3];
    const float* W_s    = (const float*)d_in[4];
    const float* b_s    = (const float*)d_in[5];
    const float* W_c    = (const float*)d_in[6];
    const float* b_c    = (const float*)d_in[7];
    const float* att_src_cs = (const float*)d_in[8];
    const float* att_dst_cs = (const float*)d_in[9];
    const float* att_src_ss = (const float*)d_in[10];
    const float* att_dst_ss = (const float*)d_in[11];
    const float* k_w  = (const float*)d_in[12];
    const float* k_b  = (const float*)d_in[13];
    const float* q    = (const float*)d_in[14];
    const float* lw   = (const float*)d_in[15];
    const float* lb   = (const float*)d_in[16];

    const int Ns  = in_sizes[0] / DIN;
    const int Nc  = in_sizes[1] / DIN;
    const int Ecs = in_sizes[2] / 2;
    const int Ess = in_sizes[3] / 2;

    // ---- workspace layout (all chunks 16B-aligned) ----
    char* p = (char*)d_ws;
    unsigned short* hbf_s = (unsigned short*)p; p += (size_t)Ns * FOUT * 2;
    unsigned short* hbf_c = (unsigned short*)p; p += (size_t)Nc * FOUT * 2;
    float* a_src_cs_ = (float*)p; p += (size_t)Nc * HH * 4;
    float* a_dst_cs_ = (float*)p; p += (size_t)Ns * HH * 4;
    float* a_src_ss_ = (float*)p; p += (size_t)Ns * HH * 4;
    float* a_dst_ss_ = (float*)p; p += (size_t)Ns * HH * 4;
    float* o1        = (float*)p; p += (size_t)Ns * FOUT * 4;
    float* o2        = (float*)p; p += (size_t)Ns * FOUT * 4;
    int* srclist_cs  = (int*)p;   p += (size_t)Ecs * 4;
    int* srclist_ss  = (int*)p;   p += (size_t)Ess * 4;
    int* rowptr_cs   = (int*)p;   p += (size_t)Ns * 4;
    int* rowptr_ss   = (int*)p;   p += (size_t)Ns * 4;
    int* bsum0       = (int*)p;   p += 2048;
    int* bsum1       = (int*)p;   p += 2048;
    // zeroed region:
    char* zstart = p;
    int* deg_cs = (int*)p; p += (size_t)Ns * 4;
    int* deg_ss = (int*)p; p += (size_t)Ns * 4;
    int* cnt_cs = (int*)p; p += (size_t)Ns * 4;
    int* cnt_ss = (int*)p; p += (size_t)Ns * 4;
    float* score = (float*)p; p += 16;   // [s0, s1, attn0, attn1]
    hipMemsetAsync(zstart, 0, (size_t)Ns * 4 * 4 + 16, stream);

    const int nbN = (Ns + 255) / 256;
    const int nbE = ((Ecs > Ess ? Ecs : Ess) + 255) / 256;
    const int Nmax = Ns > Nc ? Ns : Nc;
    const int gx_lin = ((Nmax + 15) / 16 + 3) / 4;

    // feature transforms + logits (both node types), one dispatch
    k_linm<<<dim3(gx_lin, 2), dim3(256), 0, stream>>>(
        x_subj, W_s, b_s, att_dst_cs, att_src_ss, att_dst_ss,
        hbf_s, a_dst_cs_, a_src_ss_, a_dst_ss_, Ns, 3,
        x_chan, W_c, b_c, att_src_cs, att_src_cs, att_src_cs,
        hbf_c, a_src_cs_, a_src_cs_, a_src_cs_, Nc, 1);

    // CSR build, both edge types per dispatch
    k_deg2<<<dim3(nbE), dim3(256), 0, stream>>>(e_cs, Ecs, deg_cs, e_ss, Ess, deg_ss);
    k_scan_block2<<<dim3(nbN, 2), dim3(256), 0, stream>>>(
        deg_cs, rowptr_cs, bsum0, deg_ss, rowptr_ss, bsum1, Ns);
    k_scan_partial2<<<dim3(2), dim3(512), 0, stream>>>(bsum0, bsum1, nbN);
    k_scan_add2<<<dim3(nbN, 2), dim3(256), 0, stream>>>(rowptr_cs, bsum0, rowptr_ss, bsum1, Ns);
    k_scatter2<<<dim3(nbE), dim3(256), 0, stream>>>(
        e_cs, Ecs, rowptr_cs, cnt_cs, srclist_cs,
        e_ss, Ess, rowptr_ss, cnt_ss, srclist_ss);

    // aggregation (fused softmax-normalize + relu), both metapaths
    k_agg2<<<dim3(((size_t)Ns * 32 + 255) / 256, 2), dim3(256), 0, stream>>>(
        srclist_cs, rowptr_cs, deg_cs, hbf_c, a_src_cs_, a_dst_cs_, o1,
        srclist_ss, rowptr_ss, deg_ss, hbf_s, a_src_ss_, a_dst_ss_, o2, Ns);

    // semantic attention + fuse + output
    k_sem<<<dim3(nbN, 2), dim3(256), 0, stream>>>(o1, o2, k_w, k_b, q, score, Ns);
    k_attn<<<dim3(1), dim3(64), 0, stream>>>(score, score + 2, 1.f / (float)Ns);
    k_final<<<dim3(nbN), dim3(256), 0, stream>>>(o1, o2, score + 2, lw, lb, (float*)d_out, Ns);
}

// Round 5
// 293.086 us; speedup vs baseline: 1.4457x; 1.0275x over previous
//
#include <hip/hip_runtime.h>

#define HH 8
#define FOUT 128
#define DIN 64
#define NCOL 160          // 128 h cols + 24 logit cols + 8 pad (10 MFMA j-tiles)
#define NSLOPE 0.2f
#define HR 4096           // dst-range per CSR bin (16 KB LDS histogram)
#define CHUNKN 20         // edge-slice chunks per bin

typedef __attribute__((ext_vector_type(8))) short bf16x8;
typedef __attribute__((ext_vector_type(4))) float f32x4;

__device__ __forceinline__ float fast_rcp(float x) { return __builtin_amdgcn_rcpf(x); }

__device__ __forceinline__ float fast_tanh(float x) {
    float ax = fabsf(x);
    float e = __expf(-2.f * ax);
    float r = (1.f - e) * fast_rcp(1.f + e);
    return x >= 0.f ? r : -r;
}

__device__ __forceinline__ unsigned short f2bf(float f) {
    unsigned u = __builtin_bit_cast(unsigned, f);
    unsigned r = (u + 0x7fffu + ((u >> 16) & 1u)) >> 16;
    return (unsigned short)r;
}

__device__ __forceinline__ float bf2f(unsigned short u) {
    return __builtin_bit_cast(float, (unsigned)u << 16);
}

// ---------------- feature transform via MFMA, logits as augmented GEMM columns ----------------
__global__ __launch_bounds__(256) void k_linm(
    const float* __restrict__ x0, const float* __restrict__ W0, const float* __restrict__ b0,
    const float* __restrict__ A00, const float* __restrict__ A01, const float* __restrict__ A02,
    unsigned short* __restrict__ h0,
    float* __restrict__ a00, float* __restrict__ a01, float* __restrict__ a02, int N0, int natt0,
    const float* __restrict__ x1, const float* __restrict__ W1, const float* __restrict__ b1,
    const float* __restrict__ A10, const float* __restrict__ A11, const float* __restrict__ A12,
    unsigned short* __restrict__ h1,
    float* __restrict__ a10, float* __restrict__ a11, float* __restrict__ a12, int N1, int natt1)
{
    const int y = blockIdx.y;
    const float* __restrict__ x  = y ? x1 : x0;
    const float* __restrict__ W  = y ? W1 : W0;
    const float* __restrict__ b  = y ? b1 : b0;
    const float* __restrict__ at0 = y ? A10 : A00;
    const float* __restrict__ at1 = y ? A11 : A01;
    const float* __restrict__ at2 = y ? A12 : A02;
    unsigned short* __restrict__ hb = y ? h1 : h0;
    float* __restrict__ a0 = y ? a10 : a00;
    float* __restrict__ a1 = y ? a11 : a01;
    float* __restrict__ a2 = y ? a12 : a02;
    const int N = y ? N1 : N0;
    const int natt = y ? natt1 : natt0;

    __shared__ unsigned short wtl[NCOL * DIN];  // W^T bf16, chunk-XOR swizzled (20 KB)
    __shared__ float attl[3][FOUT];
    __shared__ float bl[FOUT];
    __shared__ float abias[32];
    const int tid = threadIdx.x;

    if (tid < FOUT) {
        bl[tid] = b[tid];
        attl[0][tid] = at0[tid];
        attl[1][tid] = at1[tid];
        attl[2][tid] = at2[tid];
    }
    __syncthreads();

    for (int idx = tid; idx < DIN * FOUT; idx += 256) {
        int fi = idx >> 7, fo = idx & 127;
        wtl[fo * DIN + (((fi >> 3) ^ (fo & 7)) << 3) + (fi & 7)] = f2bf(W[idx]);
    }
    for (int idx = tid; idx < 2048; idx += 256) {
        int fi = idx >> 5, cs = idx & 31;
        float acc = 0.f;
        if (cs < 24) {
            int a = cs >> 3, hd = cs & 7;
            #pragma unroll
            for (int d = 0; d < 16; d++)
                acc += W[fi * FOUT + hd * 16 + d] * attl[a][hd * 16 + d];
        }
        int fo = 128 + cs;
        wtl[fo * DIN + (((fi >> 3) ^ (fo & 7)) << 3) + (fi & 7)] =
            cs < 24 ? f2bf(acc) : (unsigned short)0;
    }
    if (tid < 32) {
        float acc = 0.f;
        if (tid < 24) {
            int a = tid >> 3, hd = tid & 7;
            #pragma unroll
            for (int d = 0; d < 16; d++) acc += b[hd * 16 + d] * attl[a][hd * 16 + d];
        }
        abias[tid] = acc;
    }
    __syncthreads();

    const int w = tid >> 6, lane = tid & 63;
    const int rt = blockIdx.x * 4 + w;
    if (rt * 16 >= N) return;
    const int r16 = lane & 15, g = lane >> 4;

    int node = rt * 16 + r16;
    if (node >= N) node = N - 1;
    const float* xr = x + (size_t)node * DIN;
    bf16x8 af[2];
    #pragma unroll
    for (int kk = 0; kk < 2; kk++) {
        float4 v0 = *(const float4*)(xr + kk * 32 + g * 8);
        float4 v1 = *(const float4*)(xr + kk * 32 + g * 8 + 4);
        bf16x8 f;
        f[0] = (short)f2bf(v0.x); f[1] = (short)f2bf(v0.y);
        f[2] = (short)f2bf(v0.z); f[3] = (short)f2bf(v0.w);
        f[4] = (short)f2bf(v1.x); f[5] = (short)f2bf(v1.y);
        f[6] = (short)f2bf(v1.z); f[7] = (short)f2bf(v1.w);
        af[kk] = f;
    }

    #pragma unroll
    for (int j = 0; j < 10; j++) {
        const int fo = j * 16 + r16;
        f32x4 acc = {0.f, 0.f, 0.f, 0.f};
        #pragma unroll
        for (int kk = 0; kk < 2; kk++) {
            int c = (kk * 4 + g) ^ (fo & 7);
            bf16x8 bfr = *(bf16x8*)&wtl[fo * DIN + c * 8];
            acc = __builtin_amdgcn_mfma_f32_16x16x32_bf16(af[kk], bfr, acc, 0, 0, 0);
        }
        if (j < 8) {
            float bv = bl[fo];
            #pragma unroll
            for (int r = 0; r < 4; r++) {
                int nr = rt * 16 + g * 4 + r;
                if (nr < N) hb[(size_t)nr * FOUT + fo] = f2bf(acc[r] + bv);
            }
        } else {
            int cs = (j - 8) * 16 + r16;
            if (cs < 24) {
                int a = cs >> 3;
                if (a < natt) {
                    float* __restrict__ ga = a == 0 ? a0 : (a == 1 ? a1 : a2);
                    int hd = cs & 7;
                    float ab = abias[cs];
                    #pragma unroll
                    for (int r = 0; r < 4; r++) {
                        int nr = rt * 16 + g * 4 + r;
                        if (nr < N) ga[(size_t)nr * HH + hd] = acc[r] + ab;
                    }
                }
            }
        }
    }
}

// ---------------- binned CSR build: degree via LDS histogram ----------------
__global__ __launch_bounds__(256) void k_degb(
    const int* __restrict__ e0, int E0, int* __restrict__ d0,
    const int* __restrict__ e1, int E1, int* __restrict__ d1,
    int N, int nbin)
{
    int bx = blockIdx.x;
    const int half = nbin * CHUNKN;
    const bool type = bx >= half;
    if (type) bx -= half;
    const int bin = bx / CHUNKN, chunk = bx % CHUNKN;
    const int* __restrict__ e = type ? e1 : e0;
    const int E = type ? E1 : E0;
    int* __restrict__ deg = type ? d1 : d0;
    const int lo = bin * HR;

    __shared__ int hist[HR];
    for (int j = threadIdx.x; j < HR; j += 256) hist[j] = 0;
    __syncthreads();

    const int per = (E + CHUNKN - 1) / CHUNKN;
    const int s0 = chunk * per;
    const int s1 = s0 + per < E ? s0 + per : E;
    for (int i = s0 + threadIdx.x; i < s1; i += 256) {
        unsigned r = (unsigned)(e[E + i] - lo);
        if (r < HR) atomicAdd(&hist[r], 1);
    }
    __syncthreads();
    for (int j = threadIdx.x; j < HR; j += 256) {
        int v = hist[j];
        if (v && lo + j < N) atomicAdd(&deg[lo + j], v);
    }
}

// ---------------- scans (unchanged) ----------------
__global__ __launch_bounds__(256) void k_scan_block2(
    const int* __restrict__ in0, int* __restrict__ out0, int* __restrict__ bs0,
    const int* __restrict__ in1, int* __restrict__ out1, int* __restrict__ bs1, int n)
{
    const int* in = blockIdx.y ? in1 : in0;
    int* out = blockIdx.y ? out1 : out0;
    int* bsum = blockIdx.y ? bs1 : bs0;
    __shared__ int s[256];
    const int tid = threadIdx.x;
    const int i = blockIdx.x * 256 + tid;
    int v = i < n ? in[i] : 0;
    s[tid] = v; __syncthreads();
    for (int off = 1; off < 256; off <<= 1) {
        int t = tid >= off ? s[tid - off] : 0;
        __syncthreads();
        s[tid] += t;
        __syncthreads();
    }
    if (i < n) out[i] = s[tid] - v;
    if (tid == 255) bsum[blockIdx.x] = s[255];
}

__global__ __launch_bounds__(512) void k_scan_partial2(int* __restrict__ b0, int* __restrict__ b1, int nb) {
    int* bs = blockIdx.x ? b1 : b0;
    __shared__ int s[512];
    const int tid = threadIdx.x;
    int v = tid < nb ? bs[tid] : 0;
    s[tid] = v; __syncthreads();
    for (int off = 1; off < 512; off <<= 1) {
        int t = tid >= off ? s[tid - off] : 0;
        __syncthreads();
        s[tid] += t;
        __syncthreads();
    }
    if (tid < nb) bs[tid] = s[tid] - v;
}

__global__ __launch_bounds__(256) void k_scan_add2(
    int* __restrict__ o0, const int* __restrict__ b0,
    int* __restrict__ o1, const int* __restrict__ b1, int n)
{
    int* out = blockIdx.y ? o1 : o0;
    const int* bsum = blockIdx.y ? b1 : b0;
    int i = blockIdx.x * 256 + threadIdx.x;
    if (i < n) out[i] += bsum[blockIdx.x];
}

// ---------------- binned scatter: writes land dense per bin window ----------------
__global__ __launch_bounds__(256) void k_scatb(
    const int* __restrict__ e0, int E0, const int* __restrict__ rp0, int* __restrict__ c0, int* __restrict__ sl0,
    const int* __restrict__ e1, int E1, const int* __restrict__ rp1, int* __restrict__ c1, int* __restrict__ sl1,
    int nbin)
{
    int bx = blockIdx.x;
    const int half = nbin * CHUNKN;
    const bool type = bx >= half;
    if (type) bx -= half;
    const int bin = bx / CHUNKN, chunk = bx % CHUNKN;
    const int* __restrict__ e = type ? e1 : e0;
    const int E = type ? E1 : E0;
    const int* __restrict__ rp = type ? rp1 : rp0;
    int* __restrict__ cnt = type ? c1 : c0;
    int* __restrict__ sl = type ? sl1 : sl0;
    const int lo = bin * HR;

    const int per = (E + CHUNKN - 1) / CHUNKN;
    const int s0 = chunk * per;
    const int s1 = s0 + per < E ? s0 + per : E;
    for (int i = s0 + threadIdx.x; i < s1; i += 256) {
        int dst = e[E + i];
        unsigned r = (unsigned)(dst - lo);
        if (r < HR) {
            int src = e[i];
            int pos = rp[dst] + atomicAdd(&cnt[dst], 1);
            sl[pos] = src;
        }
    }
}

// ---------------- aggregation: 32 lanes per dst, bf16 gathers, bf16 o output ----------------
__global__ __launch_bounds__(256) void k_agg2(
    const int* __restrict__ sl0, const int* __restrict__ rp0, const int* __restrict__ dg0,
    const unsigned short* __restrict__ xb0, const float* __restrict__ as0, const float* __restrict__ ad0,
    unsigned short* __restrict__ oo0,
    const int* __restrict__ sl1, const int* __restrict__ rp1, const int* __restrict__ dg1,
    const unsigned short* __restrict__ xb1, const float* __restrict__ as1, const float* __restrict__ ad1,
    unsigned short* __restrict__ oo1,
    int N)
{
    const bool m = blockIdx.y;
    const int* __restrict__ sl = m ? sl1 : sl0;
    const int* __restrict__ rp = m ? rp1 : rp0;
    const int* __restrict__ dg = m ? dg1 : dg0;
    const unsigned short* __restrict__ xb = m ? xb1 : xb0;
    const float* __restrict__ as_ = m ? as1 : as0;
    const float* __restrict__ ad_ = m ? ad1 : ad0;
    unsigned short* __restrict__ oo = m ? oo1 : oo0;

    const int t = blockIdx.x * 256 + threadIdx.x;
    const int dst = t >> 5;
    if (dst >= N) return;
    const int lane = t & 31;
    const int h = lane >> 2;
    const int d = dg[dst];
    const int base = rp[dst];
    const float adv = ad_[(size_t)dst * HH + h];
    float acc0 = 0.f, acc1 = 0.f, acc2 = 0.f, acc3 = 0.f;
    float wsum = 0.f;
    int src_next = d > 0 ? sl[base] : 0;
    for (int k = 0; k < d; k++) {
        int src = src_next;
        if (k + 1 < d) src_next = sl[base + k + 1];
        float a = as_[(size_t)src * HH + h] + adv;
        a = a > 0.f ? a : NSLOPE * a;
        float wv = __expf(a);
        uint2 xv = *(const uint2*)(xb + (size_t)src * FOUT + lane * 4);
        acc0 = fmaf(wv, bf2f((unsigned short)(xv.x & 0xffff)), acc0);
        acc1 = fmaf(wv, bf2f((unsigned short)(xv.x >> 16)), acc1);
        acc2 = fmaf(wv, bf2f((unsigned short)(xv.y & 0xffff)), acc2);
        acc3 = fmaf(wv, bf2f((unsigned short)(xv.y >> 16)), acc3);
        wsum += wv;
    }
    float inv = fast_rcp(wsum + 1e-16f);
    unsigned p0 = ((unsigned)f2bf(fmaxf(acc1 * inv, 0.f)) << 16) | f2bf(fmaxf(acc0 * inv, 0.f));
    unsigned p1 = ((unsigned)f2bf(fmaxf(acc3 * inv, 0.f)) << 16) | f2bf(fmaxf(acc2 * inv, 0.f));
    *(uint2*)(oo + (size_t)dst * FOUT + lane * 4) = make_uint2(p0, p1);
}

// ---------------- semantic score: bf16 MFMA GEMM + tanh·q reduce (o already bf16) ----------------
__global__ __launch_bounds__(256) void k_sem(
    const unsigned short* __restrict__ o1, const unsigned short* __restrict__ o2,
    const float* __restrict__ kw, const float* __restrict__ kb,
    const float* __restrict__ q, float* __restrict__ score, int N)
{
    __shared__ unsigned short kwl[FOUT * FOUT];  // kw^T bf16, chunk-XOR swizzled
    __shared__ float red[256];
    const int tid = threadIdx.x;
    const int m = blockIdx.y;
    const unsigned short* o = m ? o2 : o1;

    for (int idx = tid; idx < FOUT * FOUT; idx += 256) {
        int fi = idx >> 7, fo = idx & 127;
        int c = (fi >> 3) ^ (fo & 15);
        kwl[fo * 128 + c * 8 + (fi & 7)] = f2bf(kw[idx]);
    }
    __syncthreads();

    const int lane = tid & 63;
    const int w = tid >> 6;
    const int n0 = blockIdx.x * 256 + w * 64;
    const int r16 = lane & 15;
    const int g = lane >> 4;

    float qv[8], kbv[8];
    #pragma unroll
    for (int j = 0; j < 8; j++) { qv[j] = q[j * 16 + r16]; kbv[j] = kb[j * 16 + r16]; }

    bf16x8 afrag[4][4];
    #pragma unroll
    for (int i = 0; i < 4; i++) {
        int node = n0 + i * 16 + r16;
        if (node > N - 1) node = N - 1;
        const unsigned short* rowp = o + (size_t)node * FOUT + g * 8;
        #pragma unroll
        for (int kk = 0; kk < 4; kk++)
            afrag[i][kk] = *(const bf16x8*)(rowp + kk * 32);
    }

    float part = 0.f;
    #pragma unroll
    for (int j = 0; j < 8; j++) {
        const int fo = j * 16 + r16;
        f32x4 acc0 = {0.f,0.f,0.f,0.f}, acc1 = {0.f,0.f,0.f,0.f};
        f32x4 acc2 = {0.f,0.f,0.f,0.f}, acc3 = {0.f,0.f,0.f,0.f};
        #pragma unroll
        for (int kk = 0; kk < 4; kk++) {
            int c = (kk * 4 + g) ^ (fo & 15);
            bf16x8 bfr = *(bf16x8*)&kwl[fo * 128 + c * 8];
            acc0 = __builtin_amdgcn_mfma_f32_16x16x32_bf16(afrag[0][kk], bfr, acc0, 0, 0, 0);
            acc1 = __builtin_amdgcn_mfma_f32_16x16x32_bf16(afrag[1][kk], bfr, acc1, 0, 0, 0);
            acc2 = __builtin_amdgcn_mfma_f32_16x16x32_bf16(afrag[2][kk], bfr, acc2, 0, 0, 0);
            acc3 = __builtin_amdgcn_mfma_f32_16x16x32_bf16(afrag[3][kk], bfr, acc3, 0, 0, 0);
        }
        #pragma unroll
        for (int i = 0; i < 4; i++) {
            f32x4 a = i == 0 ? acc0 : (i == 1 ? acc1 : (i == 2 ? acc2 : acc3));
            #pragma unroll
            for (int r = 0; r < 4; r++) {
                int node = n0 + i * 16 + g * 4 + r;
                if (node < N) part += fast_tanh(a[r] + kbv[j]) * qv[j];
            }
        }
    }
    red[tid] = part;
    __syncthreads();
    for (int s2 = 128; s2 > 0; s2 >>= 1) {
        if (tid < s2) red[tid] += red[tid + s2];
        __syncthreads();
    }
    if (tid == 0) atomicAdd(score + m, red[0]);
}

__global__ void k_attn(const float* __restrict__ score, float* __restrict__ attn, float invN) {
    if (threadIdx.x == 0) {
        float s0 = score[0] * invN, s1 = score[1] * invN;
        float mm = fmaxf(s0, s1);
        float e0 = __expf(s0 - mm), e1 = __expf(s1 - mm);
        float inv = 1.f / (e0 + e1);
        attn[0] = e0 * inv;
        attn[1] = e1 * inv;
    }
}

__global__ __launch_bounds__(256) void k_final(
    const unsigned short* __restrict__ o1, const unsigned short* __restrict__ o2,
    const float* __restrict__ attn,
    const float* __restrict__ lw, const float* __restrict__ lb,
    float* __restrict__ out, int N)
{
    __shared__ float lwl[FOUT * 2];
    const int tid = threadIdx.x;
    if (tid < FOUT * 2) lwl[tid] = lw[tid];
    __syncthreads();
    const int n = blockIdx.x * 256 + tid;
    if (n >= N) return;
    const float a0 = attn[0], a1 = attn[1];
    float acc0 = lb[0], acc1 = lb[1];
    const uint4* p1 = (const uint4*)(o1 + (size_t)n * FOUT);
    const uint4* p2 = (const uint4*)(o2 + (size_t)n * FOUT);
    #pragma unroll
    for (int i = 0; i < FOUT / 8; i++) {   // 8 bf16 per uint4
        uint4 v1 = p1[i];
        uint4 v2 = p2[i];
        const unsigned w1[4] = {v1.x, v1.y, v1.z, v1.w};
        const unsigned w2[4] = {v2.x, v2.y, v2.z, v2.w};
        #pragma unroll
        for (int c = 0; c < 4; c++) {
            int f = i * 8 + c * 2;
            float f0 = a0 * bf2f((unsigned short)(w1[c] & 0xffff)) +
                       a1 * bf2f((unsigned short)(w2[c] & 0xffff));
            float f1 = a0 * bf2f((unsigned short)(w1[c] >> 16)) +
                       a1 * bf2f((unsigned short)(w2[c] >> 16));
            acc0 += f0 * lwl[f*2]   + f1 * lwl[(f+1)*2];
            acc1 += f0 * lwl[f*2+1] + f1 * lwl[(f+1)*2+1];
        }
    }
    *(float2*)(out + (size_t)n * 2) = make_float2(acc0, acc1);
}

extern "C" void kernel_launch(void* const* d_in, const int* in_sizes, int n_in,
                              void* d_out, int out_size, void* d_ws, size_t ws_size,
                              hipStream_t stream)
{
    const float* x_subj = (const float*)d_in[0];
    const float* x_chan = (const float*)d_in[1];
    const int*   e_cs   = (const int*)d_in[2];
    const int*   e_ss   = (const int*)d_in[3];
    const float* W_s    = (const float*)d_in[4];
    const float* b_s    = (const float*)d_in[5];
    const float* W_c    = (const float*)d_in[6];
    const float* b_c    = (const float*)d_in[7];
    const float* att_src_cs = (const float*)d_in[8];
    const float* att_dst_cs = (const float*)d_in[9];
    const float* att_src_ss = (const float*)d_in[10];
    const float* att_dst_ss = (const float*)d_in[11];
    const float* k_w  = (const float*)d_in[12];
    const float* k_b  = (const float*)d_in[13];
    const float* q    = (const float*)d_in[14];
    const float* lw   = (const float*)d_in[15];
    const float* lb   = (const float*)d_in[16];

    const int Ns  = in_sizes[0] / DIN;
    const int Nc  = in_sizes[1] / DIN;
    const int Ecs = in_sizes[2] / 2;
    const int Ess = in_sizes[3] / 2;

    // ---- workspace layout (all chunks 16B-aligned) ----
    char* p = (char*)d_ws;
    unsigned short* hbf_s = (unsigned short*)p; p += (size_t)Ns * FOUT * 2;
    unsigned short* hbf_c = (unsigned short*)p; p += (size_t)Nc * FOUT * 2;
    float* a_src_cs_ = (float*)p; p += (size_t)Nc * HH * 4;
    float* a_dst_cs_ = (float*)p; p += (size_t)Ns * HH * 4;
    float* a_src_ss_ = (float*)p; p += (size_t)Ns * HH * 4;
    float* a_dst_ss_ = (float*)p; p += (size_t)Ns * HH * 4;
    unsigned short* o1 = (unsigned short*)p; p += (size_t)Ns * FOUT * 2;
    unsigned short* o2 = (unsigned short*)p; p += (size_t)Ns * FOUT * 2;
    int* srclist_cs  = (int*)p;   p += (size_t)Ecs * 4;
    int* srclist_ss  = (int*)p;   p += (size_t)Ess * 4;
    int* rowptr_cs   = (int*)p;   p += (size_t)Ns * 4;
    int* rowptr_ss   = (int*)p;   p += (size_t)Ns * 4;
    int* bsum0       = (int*)p;   p += 2048;
    int* bsum1       = (int*)p;   p += 2048;
    // zeroed region:
    char* zstart = p;
    int* deg_cs = (int*)p; p += (size_t)Ns * 4;
    int* deg_ss = (int*)p; p += (size_t)Ns * 4;
    int* cnt_cs = (int*)p; p += (size_t)Ns * 4;
    int* cnt_ss = (int*)p; p += (size_t)Ns * 4;
    float* score = (float*)p; p += 16;   // [s0, s1, attn0, attn1]
    hipMemsetAsync(zstart, 0, (size_t)Ns * 4 * 4 + 16, stream);

    const int nbN = (Ns + 255) / 256;
    const int Nmax = Ns > Nc ? Ns : Nc;
    const int gx_lin = ((Nmax + 15) / 16 + 3) / 4;
    const int nbin = (Ns + HR - 1) / HR;

    // feature transforms + logits (both node types), one dispatch
    k_linm<<<dim3(gx_lin, 2), dim3(256), 0, stream>>>(
        x_subj, W_s, b_s, att_dst_cs, att_src_ss, att_dst_ss,
        hbf_s, a_dst_cs_, a_src_ss_, a_dst_ss_, Ns, 3,
        x_chan, W_c, b_c, att_src_cs, att_src_cs, att_src_cs,
        hbf_c, a_src_cs_, a_src_cs_, a_src_cs_, Nc, 1);

    // binned CSR build (both edge types per dispatch)
    k_degb<<<dim3(nbin * CHUNKN * 2), dim3(256), 0, stream>>>(
        e_cs, Ecs, deg_cs, e_ss, Ess, deg_ss, Ns, nbin);
    k_scan_block2<<<dim3(nbN, 2), dim3(256), 0, stream>>>(
        deg_cs, rowptr_cs, bsum0, deg_ss, rowptr_ss, bsum1, Ns);
    k_scan_partial2<<<dim3(2), dim3(512), 0, stream>>>(bsum0, bsum1, nbN);
    k_scan_add2<<<dim3(nbN, 2), dim3(256), 0, stream>>>(rowptr_cs, bsum0, rowptr_ss, bsum1, Ns);
    k_scatb<<<dim3(nbin * CHUNKN * 2), dim3(256), 0, stream>>>(
        e_cs, Ecs, rowptr_cs, cnt_cs, srclist_cs,
        e_ss, Ess, rowptr_ss, cnt_ss, srclist_ss, nbin);

    // aggregation (fused softmax-normalize + relu), both metapaths
    k_agg2<<<dim3(((size_t)Ns * 32 + 255) / 256, 2), dim3(256), 0, stream>>>(
        srclist_cs, rowptr_cs, deg_cs, hbf_c, a_src_cs_, a_dst_cs_, o1,
        srclist_ss, rowptr_ss, deg_ss, hbf_s, a_src_ss_, a_dst_ss_, o2, Ns);

    // semantic attention + fuse + output
    k_sem<<<dim3(nbN, 2), dim3(256), 0, stream>>>(o1, o2, k_w, k_b, q, score, Ns);
    k_attn<<<dim3(1), dim3(64), 0, stream>>>(score, score + 2, 1.f / (float)Ns);
    k_final<<<dim3(nbN), dim3(256), 0, stream>>>(o1, o2, score + 2, lw, lb, (float*)d_out, Ns);
}

// Round 6
// 292.307 us; speedup vs baseline: 1.4495x; 1.0027x over previous
//
#include <hip/hip_runtime.h>

#define HH 8
#define FOUT 128
#define DIN 64
#define NCOL 160          // 128 h cols + 24 logit cols + 8 pad (10 MFMA j-tiles)
#define NSLOPE 0.2f
#define HR 4096           // dst-range per CSR bin (16 KB LDS histogram)
#define CHUNKN 20         // edge-slice chunks per bin

typedef __attribute__((ext_vector_type(8))) short bf16x8;
typedef __attribute__((ext_vector_type(4))) float f32x4;

__device__ __forceinline__ float fast_rcp(float x) { return __builtin_amdgcn_rcpf(x); }

__device__ __forceinline__ float fast_tanh(float x) {
    float ax = fabsf(x);
    float e = __expf(-2.f * ax);
    float r = (1.f - e) * fast_rcp(1.f + e);
    return x >= 0.f ? r : -r;
}

__device__ __forceinline__ unsigned short f2bf(float f) {
    unsigned u = __builtin_bit_cast(unsigned, f);
    unsigned r = (u + 0x7fffu + ((u >> 16) & 1u)) >> 16;
    return (unsigned short)r;
}

__device__ __forceinline__ float bf2f(unsigned short u) {
    return __builtin_bit_cast(float, (unsigned)u << 16);
}

// ---------------- feature transform via MFMA, logits as augmented GEMM columns ----------------
__global__ __launch_bounds__(256) void k_linm(
    const float* __restrict__ x0, const float* __restrict__ W0, const float* __restrict__ b0,
    const float* __restrict__ A00, const float* __restrict__ A01, const float* __restrict__ A02,
    unsigned short* __restrict__ h0,
    float* __restrict__ a00, float* __restrict__ a01, float* __restrict__ a02, int N0, int natt0,
    const float* __restrict__ x1, const float* __restrict__ W1, const float* __restrict__ b1,
    const float* __restrict__ A10, const float* __restrict__ A11, const float* __restrict__ A12,
    unsigned short* __restrict__ h1,
    float* __restrict__ a10, float* __restrict__ a11, float* __restrict__ a12, int N1, int natt1)
{
    const int y = blockIdx.y;
    const float* __restrict__ x  = y ? x1 : x0;
    const float* __restrict__ W  = y ? W1 : W0;
    const float* __restrict__ b  = y ? b1 : b0;
    const float* __restrict__ at0 = y ? A10 : A00;
    const float* __restrict__ at1 = y ? A11 : A01;
    const float* __restrict__ at2 = y ? A12 : A02;
    unsigned short* __restrict__ hb = y ? h1 : h0;
    float* __restrict__ a0 = y ? a10 : a00;
    float* __restrict__ a1 = y ? a11 : a01;
    float* __restrict__ a2 = y ? a12 : a02;
    const int N = y ? N1 : N0;
    const int natt = y ? natt1 : natt0;

    __shared__ unsigned short wtl[NCOL * DIN];  // W^T bf16, chunk-XOR swizzled (20 KB)
    __shared__ float attl[3][FOUT];
    __shared__ float bl[FOUT];
    __shared__ float abias[32];
    const int tid = threadIdx.x;

    if (tid < FOUT) {
        bl[tid] = b[tid];
        attl[0][tid] = at0[tid];
        attl[1][tid] = at1[tid];
        attl[2][tid] = at2[tid];
    }
    __syncthreads();

    for (int idx = tid; idx < DIN * FOUT; idx += 256) {
        int fi = idx >> 7, fo = idx & 127;
        wtl[fo * DIN + (((fi >> 3) ^ (fo & 7)) << 3) + (fi & 7)] = f2bf(W[idx]);
    }
    for (int idx = tid; idx < 2048; idx += 256) {
        int fi = idx >> 5, cs = idx & 31;
        float acc = 0.f;
        if (cs < 24) {
            int a = cs >> 3, hd = cs & 7;
            #pragma unroll
            for (int d = 0; d < 16; d++)
                acc += W[fi * FOUT + hd * 16 + d] * attl[a][hd * 16 + d];
        }
        int fo = 128 + cs;
        wtl[fo * DIN + (((fi >> 3) ^ (fo & 7)) << 3) + (fi & 7)] =
            cs < 24 ? f2bf(acc) : (unsigned short)0;
    }
    if (tid < 32) {
        float acc = 0.f;
        if (tid < 24) {
            int a = tid >> 3, hd = tid & 7;
            #pragma unroll
            for (int d = 0; d < 16; d++) acc += b[hd * 16 + d] * attl[a][hd * 16 + d];
        }
        abias[tid] = acc;
    }
    __syncthreads();

    const int w = tid >> 6, lane = tid & 63;
    const int rt = blockIdx.x * 4 + w;
    if (rt * 16 >= N) return;
    const int r16 = lane & 15, g = lane >> 4;

    int node = rt * 16 + r16;
    if (node >= N) node = N - 1;
    const float* xr = x + (size_t)node * DIN;
    bf16x8 af[2];
    #pragma unroll
    for (int kk = 0; kk < 2; kk++) {
        float4 v0 = *(const float4*)(xr + kk * 32 + g * 8);
        float4 v1 = *(const float4*)(xr + kk * 32 + g * 8 + 4);
        bf16x8 f;
        f[0] = (short)f2bf(v0.x); f[1] = (short)f2bf(v0.y);
        f[2] = (short)f2bf(v0.z); f[3] = (short)f2bf(v0.w);
        f[4] = (short)f2bf(v1.x); f[5] = (short)f2bf(v1.y);
        f[6] = (short)f2bf(v1.z); f[7] = (short)f2bf(v1.w);
        af[kk] = f;
    }

    #pragma unroll
    for (int j = 0; j < 10; j++) {
        const int fo = j * 16 + r16;
        f32x4 acc = {0.f, 0.f, 0.f, 0.f};
        #pragma unroll
        for (int kk = 0; kk < 2; kk++) {
            int c = (kk * 4 + g) ^ (fo & 7);
            bf16x8 bfr = *(bf16x8*)&wtl[fo * DIN + c * 8];
            acc = __builtin_amdgcn_mfma_f32_16x16x32_bf16(af[kk], bfr, acc, 0, 0, 0);
        }
        if (j < 8) {
            float bv = bl[fo];
            #pragma unroll
            for (int r = 0; r < 4; r++) {
                int nr = rt * 16 + g * 4 + r;
                if (nr < N) hb[(size_t)nr * FOUT + fo] = f2bf(acc[r] + bv);
            }
        } else {
            int cs = (j - 8) * 16 + r16;
            if (cs < 24) {
                int a = cs >> 3;
                if (a < natt) {
                    float* __restrict__ ga = a == 0 ? a0 : (a == 1 ? a1 : a2);
                    int hd = cs & 7;
                    float ab = abias[cs];
                    #pragma unroll
                    for (int r = 0; r < 4; r++) {
                        int nr = rt * 16 + g * 4 + r;
                        if (nr < N) ga[(size_t)nr * HH + hd] = acc[r] + ab;
                    }
                }
            }
        }
    }
}

// ---------------- binned CSR build: degree via LDS histogram, XCD-pinned bins ----------------
// Grid mapping: bx = chunk*nbp + tb, nbp % 8 == 0  ->  bx % 8 == tb % 8 : all chunks of one
// (type,bin) land on the same XCD, so its deg window stays in ONE L2 (no cross-XCD bounce).
__global__ __launch_bounds__(256) void k_degb(
    const int* __restrict__ e0, int E0, int* __restrict__ d0,
    const int* __restrict__ e1, int E1, int* __restrict__ d1,
    int N, int nbin, int nbp)
{
    const int bx = blockIdx.x;
    const int chunk = bx / nbp;
    const int tb = bx % nbp;
    if (tb >= 2 * nbin) return;
    const bool type = tb >= nbin;
    const int bin = type ? tb - nbin : tb;
    const int* __restrict__ e = type ? e1 : e0;
    const int E = type ? E1 : E0;
    int* __restrict__ deg = type ? d1 : d0;
    const int lo = bin * HR;

    __shared__ int hist[HR];
    for (int j = threadIdx.x; j < HR; j += 256) hist[j] = 0;
    __syncthreads();

    const int per = (E + CHUNKN - 1) / CHUNKN;
    const int s0 = chunk * per;
    const int s1 = s0 + per < E ? s0 + per : E;
    for (int i = s0 + threadIdx.x; i < s1; i += 256) {
        unsigned r = (unsigned)(e[E + i] - lo);
        if (r < HR) atomicAdd(&hist[r], 1);
    }
    __syncthreads();
    for (int j = threadIdx.x; j < HR; j += 256) {
        int v = hist[j];
        if (v && lo + j < N) atomicAdd(&deg[lo + j], v);
    }
}

// ---------------- scans (unchanged) ----------------
__global__ __launch_bounds__(256) void k_scan_block2(
    const int* __restrict__ in0, int* __restrict__ out0, int* __restrict__ bs0,
    const int* __restrict__ in1, int* __restrict__ out1, int* __restrict__ bs1, int n)
{
    const int* in = blockIdx.y ? in1 : in0;
    int* out = blockIdx.y ? out1 : out0;
    int* bsum = blockIdx.y ? bs1 : bs0;
    __shared__ int s[256];
    const int tid = threadIdx.x;
    const int i = blockIdx.x * 256 + tid;
    int v = i < n ? in[i] : 0;
    s[tid] = v; __syncthreads();
    for (int off = 1; off < 256; off <<= 1) {
        int t = tid >= off ? s[tid - off] : 0;
        __syncthreads();
        s[tid] += t;
        __syncthreads();
    }
    if (i < n) out[i] = s[tid] - v;
    if (tid == 255) bsum[blockIdx.x] = s[255];
}

__global__ __launch_bounds__(512) void k_scan_partial2(int* __restrict__ b0, int* __restrict__ b1, int nb) {
    int* bs = blockIdx.x ? b1 : b0;
    __shared__ int s[512];
    const int tid = threadIdx.x;
    int v = tid < nb ? bs[tid] : 0;
    s[tid] = v; __syncthreads();
    for (int off = 1; off < 512; off <<= 1) {
        int t = tid >= off ? s[tid - off] : 0;
        __syncthreads();
        s[tid] += t;
        __syncthreads();
    }
    if (tid < nb) bs[tid] = s[tid] - v;
}

__global__ __launch_bounds__(256) void k_scan_add2(
    int* __restrict__ o0, const int* __restrict__ b0,
    int* __restrict__ o1, const int* __restrict__ b1, int n)
{
    int* out = blockIdx.y ? o1 : o0;
    const int* bsum = blockIdx.y ? b1 : b0;
    int i = blockIdx.x * 256 + threadIdx.x;
    if (i < n) out[i] += bsum[blockIdx.x];
}

// ---------------- binned scatter, XCD-pinned bins (same mapping as k_degb) ----------------
__global__ __launch_bounds__(256) void k_scatb(
    const int* __restrict__ e0, int E0, const int* __restrict__ rp0, int* __restrict__ c0, int* __restrict__ sl0,
    const int* __restrict__ e1, int E1, const int* __restrict__ rp1, int* __restrict__ c1, int* __restrict__ sl1,
    int nbin, int nbp)
{
    const int bx = blockIdx.x;
    const int chunk = bx / nbp;
    const int tb = bx % nbp;
    if (tb >= 2 * nbin) return;
    const bool type = tb >= nbin;
    const int bin = type ? tb - nbin : tb;
    const int* __restrict__ e = type ? e1 : e0;
    const int E = type ? E1 : E0;
    const int* __restrict__ rp = type ? rp1 : rp0;
    int* __restrict__ cnt = type ? c1 : c0;
    int* __restrict__ sl = type ? sl1 : sl0;
    const int lo = bin * HR;

    const int per = (E + CHUNKN - 1) / CHUNKN;
    const int s0 = chunk * per;
    const int s1 = s0 + per < E ? s0 + per : E;
    for (int i = s0 + threadIdx.x; i < s1; i += 256) {
        int dst = e[E + i];
        unsigned r = (unsigned)(dst - lo);
        if (r < HR) {
            int src = e[i];
            int pos = rp[dst] + atomicAdd(&cnt[dst], 1);
            sl[pos] = src;
        }
    }
}

// ---------------- aggregation: 32 lanes per dst, bf16 gathers, bf16 o output ----------------
__global__ __launch_bounds__(256) void k_agg2(
    const int* __restrict__ sl0, const int* __restrict__ rp0, const int* __restrict__ dg0,
    const unsigned short* __restrict__ xb0, const float* __restrict__ as0, const float* __restrict__ ad0,
    unsigned short* __restrict__ oo0,
    const int* __restrict__ sl1, const int* __restrict__ rp1, const int* __restrict__ dg1,
    const unsigned short* __restrict__ xb1, const float* __restrict__ as1, const float* __restrict__ ad1,
    unsigned short* __restrict__ oo1,
    int N)
{
    const bool m = blockIdx.y;
    const int* __restrict__ sl = m ? sl1 : sl0;
    const int* __restrict__ rp = m ? rp1 : rp0;
    const int* __restrict__ dg = m ? dg1 : dg0;
    const unsigned short* __restrict__ xb = m ? xb1 : xb0;
    const float* __restrict__ as_ = m ? as1 : as0;
    const float* __restrict__ ad_ = m ? ad1 : ad0;
    unsigned short* __restrict__ oo = m ? oo1 : oo0;

    const int t = blockIdx.x * 256 + threadIdx.x;
    const int dst = t >> 5;
    if (dst >= N) return;
    const int lane = t & 31;
    const int h = lane >> 2;
    const int d = dg[dst];
    const int base = rp[dst];
    const float adv = ad_[(size_t)dst * HH + h];
    float acc0 = 0.f, acc1 = 0.f, acc2 = 0.f, acc3 = 0.f;
    float wsum = 0.f;
    int src_next = d > 0 ? sl[base] : 0;
    for (int k = 0; k < d; k++) {
        int src = src_next;
        if (k + 1 < d) src_next = sl[base + k + 1];
        float a = as_[(size_t)src * HH + h] + adv;
        a = a > 0.f ? a : NSLOPE * a;
        float wv = __expf(a);
        uint2 xv = *(const uint2*)(xb + (size_t)src * FOUT + lane * 4);
        acc0 = fmaf(wv, bf2f((unsigned short)(xv.x & 0xffff)), acc0);
        acc1 = fmaf(wv, bf2f((unsigned short)(xv.x >> 16)), acc1);
        acc2 = fmaf(wv, bf2f((unsigned short)(xv.y & 0xffff)), acc2);
        acc3 = fmaf(wv, bf2f((unsigned short)(xv.y >> 16)), acc3);
        wsum += wv;
    }
    float inv = fast_rcp(wsum + 1e-16f);
    unsigned p0 = ((unsigned)f2bf(fmaxf(acc1 * inv, 0.f)) << 16) | f2bf(fmaxf(acc0 * inv, 0.f));
    unsigned p1 = ((unsigned)f2bf(fmaxf(acc3 * inv, 0.f)) << 16) | f2bf(fmaxf(acc2 * inv, 0.f));
    *(uint2*)(oo + (size_t)dst * FOUT + lane * 4) = make_uint2(p0, p1);
}

// ---------------- semantic score: bf16 MFMA GEMM + tanh·q reduce (o already bf16) ----------------
__global__ __launch_bounds__(256) void k_sem(
    const unsigned short* __restrict__ o1, const unsigned short* __restrict__ o2,
    const float* __restrict__ kw, const float* __restrict__ kb,
    const float* __restrict__ q, float* __restrict__ score, int N)
{
    __shared__ unsigned short kwl[FOUT * FOUT];  // kw^T bf16, chunk-XOR swizzled
    __shared__ float red[256];
    const int tid = threadIdx.x;
    const int m = blockIdx.y;
    const unsigned short* o = m ? o2 : o1;

    for (int idx = tid; idx < FOUT * FOUT; idx += 256) {
        int fi = idx >> 7, fo = idx & 127;
        int c = (fi >> 3) ^ (fo & 15);
        kwl[fo * 128 + c * 8 + (fi & 7)] = f2bf(kw[idx]);
    }
    __syncthreads();

    const int lane = tid & 63;
    const int w = tid >> 6;
    const int n0 = blockIdx.x * 256 + w * 64;
    const int r16 = lane & 15;
    const int g = lane >> 4;

    float qv[8], kbv[8];
    #pragma unroll
    for (int j = 0; j < 8; j++) { qv[j] = q[j * 16 + r16]; kbv[j] = kb[j * 16 + r16]; }

    bf16x8 afrag[4][4];
    #pragma unroll
    for (int i = 0; i < 4; i++) {
        int node = n0 + i * 16 + r16;
        if (node > N - 1) node = N - 1;
        const unsigned short* rowp = o + (size_t)node * FOUT + g * 8;
        #pragma unroll
        for (int kk = 0; kk < 4; kk++)
            afrag[i][kk] = *(const bf16x8*)(rowp + kk * 32);
    }

    float part = 0.f;
    #pragma unroll
    for (int j = 0; j < 8; j++) {
        const int fo = j * 16 + r16;
        f32x4 acc0 = {0.f,0.f,0.f,0.f}, acc1 = {0.f,0.f,0.f,0.f};
        f32x4 acc2 = {0.f,0.f,0.f,0.f}, acc3 = {0.f,0.f,0.f,0.f};
        #pragma unroll
        for (int kk = 0; kk < 4; kk++) {
            int c = (kk * 4 + g) ^ (fo & 15);
            bf16x8 bfr = *(bf16x8*)&kwl[fo * 128 + c * 8];
            acc0 = __builtin_amdgcn_mfma_f32_16x16x32_bf16(afrag[0][kk], bfr, acc0, 0, 0, 0);
            acc1 = __builtin_amdgcn_mfma_f32_16x16x32_bf16(afrag[1][kk], bfr, acc1, 0, 0, 0);
            acc2 = __builtin_amdgcn_mfma_f32_16x16x32_bf16(afrag[2][kk], bfr, acc2, 0, 0, 0);
            acc3 = __builtin_amdgcn_mfma_f32_16x16x32_bf16(afrag[3][kk], bfr, acc3, 0, 0, 0);
        }
        #pragma unroll
        for (int i = 0; i < 4; i++) {
            f32x4 a = i == 0 ? acc0 : (i == 1 ? acc1 : (i == 2 ? acc2 : acc3));
            #pragma unroll
            for (int r = 0; r < 4; r++) {
                int node = n0 + i * 16 + g * 4 + r;
                if (node < N) part += fast_tanh(a[r] + kbv[j]) * qv[j];
            }
        }
    }
    red[tid] = part;
    __syncthreads();
    for (int s2 = 128; s2 > 0; s2 >>= 1) {
        if (tid < s2) red[tid] += red[tid + s2];
        __syncthreads();
    }
    if (tid == 0) atomicAdd(score + m, red[0]);
}

// ---------------- final: per-block softmax of the 2 scores (k_attn folded in) ----------------
__global__ __launch_bounds__(256) void k_final(
    const unsigned short* __restrict__ o1, const unsigned short* __restrict__ o2,
    const float* __restrict__ score, float invN,
    const float* __restrict__ lw, const float* __restrict__ lb,
    float* __restrict__ out, int N)
{
    __shared__ float lwl[FOUT * 2];
    __shared__ float attns[2];
    const int tid = threadIdx.x;
    if (tid < FOUT * 2) lwl[tid] = lw[tid];
    if (tid == 0) {
        float s0 = score[0] * invN, s1 = score[1] * invN;
        float mm = fmaxf(s0, s1);
        float e0 = __expf(s0 - mm), e1 = __expf(s1 - mm);
        float inv = 1.f / (e0 + e1);
        attns[0] = e0 * inv;
        attns[1] = e1 * inv;
    }
    __syncthreads();
    const int n = blockIdx.x * 256 + tid;
    if (n >= N) return;
    const float a0 = attns[0], a1 = attns[1];
    float acc0 = lb[0], acc1 = lb[1];
    const uint4* p1 = (const uint4*)(o1 + (size_t)n * FOUT);
    const uint4* p2 = (const uint4*)(o2 + (size_t)n * FOUT);
    #pragma unroll
    for (int i = 0; i < FOUT / 8; i++) {   // 8 bf16 per uint4
        uint4 v1 = p1[i];
        uint4 v2 = p2[i];
        const unsigned w1[4] = {v1.x, v1.y, v1.z, v1.w};
        const unsigned w2[4] = {v2.x, v2.y, v2.z, v2.w};
        #pragma unroll
        for (int c = 0; c < 4; c++) {
            int f = i * 8 + c * 2;
            float f0 = a0 * bf2f((unsigned short)(w1[c] & 0xffff)) +
                       a1 * bf2f((unsigned short)(w2[c] & 0xffff));
            float f1 = a0 * bf2f((unsigned short)(w1[c] >> 16)) +
                       a1 * bf2f((unsigned short)(w2[c] >> 16));
            acc0 += f0 * lwl[f*2]   + f1 * lwl[(f+1)*2];
            acc1 += f0 * lwl[f*2+1] + f1 * lwl[(f+1)*2+1];
        }
    }
    *(float2*)(out + (size_t)n * 2) = make_float2(acc0, acc1);
}

extern "C" void kernel_launch(void* const* d_in, const int* in_sizes, int n_in,
                              void* d_out, int out_size, void* d_ws, size_t ws_size,
                              hipStream_t stream)
{
    const float* x_subj = (const float*)d_in[0];
    const float* x_chan = (const float*)d_in[1];
    const int*   e_cs   = (const int*)d_in[2];
    const int*   e_ss   = (const int*)d_in[3];
    const float* W_s    = (const float*)d_in[4];
    const float* b_s    = (const float*)d_in[5];
    const float* W_c    = (const float*)d_in[6];
    const float* b_c    = (const float*)d_in[7];
    const float* att_src_cs = (const float*)d_in[8];
    const float* att_dst_cs = (const float*)d_in[9];
    const float* att_src_ss = (const float*)d_in[10];
    const float* att_dst_ss = (const float*)d_in[11];
    const float* k_w  = (const float*)d_in[12];
    const float* k_b  = (const float*)d_in[13];
    const float* q    = (const float*)d_in[14];
    const float* lw   = (const float*)d_in[15];
    const float* lb   = (const float*)d_in[16];

    const int Ns  = in_sizes[0] / DIN;
    const int Nc  = in_sizes[1] / DIN;
    const int Ecs = in_sizes[2] / 2;
    const int Ess = in_sizes[3] / 2;

    // ---- workspace layout (all chunks 16B-aligned) ----
    char* p = (char*)d_ws;
    unsigned short* hbf_s = (unsigned short*)p; p += (size_t)Ns * FOUT * 2;
    unsigned short* hbf_c = (unsigned short*)p; p += (size_t)Nc * FOUT * 2;
    float* a_src_cs_ = (float*)p; p += (size_t)Nc * HH * 4;
    float* a_dst_cs_ = (float*)p; p += (size_t)Ns * HH * 4;
    float* a_src_ss_ = (float*)p; p += (size_t)Ns * HH * 4;
    float* a_dst_ss_ = (float*)p; p += (size_t)Ns * HH * 4;
    unsigned short* o1 = (unsigned short*)p; p += (size_t)Ns * FOUT * 2;
    unsigned short* o2 = (unsigned short*)p; p += (size_t)Ns * FOUT * 2;
    int* srclist_cs  = (int*)p;   p += (size_t)Ecs * 4;
    int* srclist_ss  = (int*)p;   p += (size_t)Ess * 4;
    int* rowptr_cs   = (int*)p;   p += (size_t)Ns * 4;
    int* rowptr_ss   = (int*)p;   p += (size_t)Ns * 4;
    int* bsum0       = (int*)p;   p += 2048;
    int* bsum1       = (int*)p;   p += 2048;
    // zeroed region:
    char* zstart = p;
    int* deg_cs = (int*)p; p += (size_t)Ns * 4;
    int* deg_ss = (int*)p; p += (size_t)Ns * 4;
    int* cnt_cs = (int*)p; p += (size_t)Ns * 4;
    int* cnt_ss = (int*)p; p += (size_t)Ns * 4;
    float* score = (float*)p; p += 16;   // [s0, s1]
    hipMemsetAsync(zstart, 0, (size_t)Ns * 4 * 4 + 16, stream);

    const int nbN = (Ns + 255) / 256;
    const int Nmax = Ns > Nc ? Ns : Nc;
    const int gx_lin = ((Nmax + 15) / 16 + 3) / 4;
    const int nbin = (Ns + HR - 1) / HR;
    const int nbp = ((2 * nbin + 7) / 8) * 8;   // pad (type,bin) space to mult of 8 -> XCD pin

    // feature transforms + logits (both node types), one dispatch
    k_linm<<<dim3(gx_lin, 2), dim3(256), 0, stream>>>(
        x_subj, W_s, b_s, att_dst_cs, att_src_ss, att_dst_ss,
        hbf_s, a_dst_cs_, a_src_ss_, a_dst_ss_, Ns, 3,
        x_chan, W_c, b_c, att_src_cs, att_src_cs, att_src_cs,
        hbf_c, a_src_cs_, a_src_cs_, a_src_cs_, Nc, 1);

    // binned CSR build, XCD-pinned bins
    k_degb<<<dim3(nbp * CHUNKN), dim3(256), 0, stream>>>(
        e_cs, Ecs, deg_cs, e_ss, Ess, deg_ss, Ns, nbin, nbp);
    k_scan_block2<<<dim3(nbN, 2), dim3(256), 0, stream>>>(
        deg_cs, rowptr_cs, bsum0, deg_ss, rowptr_ss, bsum1, Ns);
    k_scan_partial2<<<dim3(2), dim3(512), 0, stream>>>(bsum0, bsum1, nbN);
    k_scan_add2<<<dim3(nbN, 2), dim3(256), 0, stream>>>(rowptr_cs, bsum0, rowptr_ss, bsum1, Ns);
    k_scatb<<<dim3(nbp * CHUNKN), dim3(256), 0, stream>>>(
        e_cs, Ecs, rowptr_cs, cnt_cs, srclist_cs,
        e_ss, Ess, rowptr_ss, cnt_ss, srclist_ss, nbin, nbp);

    // aggregation (fused softmax-normalize + relu), both metapaths
    k_agg2<<<dim3(((size_t)Ns * 32 + 255) / 256, 2), dim3(256), 0, stream>>>(
        srclist_cs, rowptr_cs, deg_cs, hbf_c, a_src_cs_, a_dst_cs_, o1,
        srclist_ss, rowptr_ss, deg_ss, hbf_s, a_src_ss_, a_dst_ss_, o2, Ns);

    // semantic attention + fuse + output
    k_sem<<<dim3(nbN, 2), dim3(256), 0, stream>>>(o1, o2, k_w, k_b, q, score, Ns);
    k_final<<<dim3(nbN), dim3(256), 0, stream>>>(
        o1, o2, score, 1.f / (float)Ns, lw, lb, (float*)d_out, Ns);
}